// Round 1
// baseline (3329.902 us; speedup 1.0000x reference)
//
#include <hip/hip_runtime.h>
#include <hip/hip_bf16.h>
#include <math.h>

// RGSLCell: two AVWGCN blocks (gate 96->128, update 96->64) + SE-style scalar
// attention + GRU combine. B=64, N=1024, DIN=32, DOUT=64, K=3, ED=16, CIN=96.
// Round 1: full fp32 baseline (no MFMA on fp32 in CDNA4). Structure:
//   supports = [I, L, 2L^2 - I]  -> only two N x N GEMMs (t1 = L@x, t2 = 2*L@t1 - x)
//   cheb path: x0 = x@iw^T+ib, then 3x cheb_k@x0, folded with gw_k row-GEMMs
//   per-node dynamic weights: one workgroup per node, weights generated in LDS

#define B_  64
#define N_  1024
#define CIN_ 96

__device__ __forceinline__ float lrelu(float v) { return v >= 0.f ? v : 0.01f * v; }
__device__ __forceinline__ float sigmoidf_(float u) { return 1.f / (1.f + expf(-u)); }

// ---------------------------------------------------------------------------
// concat inp_state = [x | state]  -> [B,N,96]
__global__ __launch_bounds__(256) void concat_xs(const float* __restrict__ x,
                                                 const float* __restrict__ st,
                                                 float* __restrict__ inp) {
  size_t t = (size_t)blockIdx.x * 256 + threadIdx.x;
  if (t >= (size_t)B_ * N_ * CIN_) return;
  int i = (int)(t % CIN_);
  size_t bn = t / CIN_;
  inp[t] = (i < 32) ? x[bn * 32 + i] : st[bn * 64 + (i - 32)];
}

// ---------------------------------------------------------------------------
// Y[b] = alpha * (S @ X[b]) + beta * E[b]   (S: [1024,1024], X: [B,1024,C])
// block: 64 rows x C cols; 256 threads; per-thread 4 x (C/16) accumulators
template <int C>
__global__ __launch_bounds__(256) void gemm_adj(const float* __restrict__ S,
                                                const float* __restrict__ X,
                                                const float* __restrict__ E,
                                                float* __restrict__ Y,
                                                float alpha, float beta) {
  constexpr int Cw = C / 16;
  const int b = blockIdx.y;
  const int m0 = blockIdx.x * 64;
  const int tid = threadIdx.x;
  const int ty = tid >> 4, tx = tid & 15;
  __shared__ float sA[32][68];      // [kk][m], padded for b128 alignment
  __shared__ float sX[32][C + 4];   // [kk][c]
  float acc[4][Cw] = {};
  const float* Xb = X + (size_t)b * N_ * C;
  const int lm = tid >> 2;          // 0..63
  const int lk = (tid & 3) * 8;     // 0,8,16,24

  for (int k0 = 0; k0 < 1024; k0 += 32) {
    __syncthreads();
    {
      const float* p = S + (size_t)(m0 + lm) * 1024 + k0 + lk;
      float4 v0 = *(const float4*)p;
      float4 v1 = *(const float4*)(p + 4);
      sA[lk + 0][lm] = v0.x; sA[lk + 1][lm] = v0.y;
      sA[lk + 2][lm] = v0.z; sA[lk + 3][lm] = v0.w;
      sA[lk + 4][lm] = v1.x; sA[lk + 5][lm] = v1.y;
      sA[lk + 6][lm] = v1.z; sA[lk + 7][lm] = v1.w;
    }
    for (int e = tid; e < 8 * C; e += 256) {  // 32*C/4 float4 loads
      int kk = e / (C / 4), c4 = e % (C / 4);
      float4 v = *(const float4*)(Xb + (size_t)(k0 + kk) * C + c4 * 4);
      int c = c4 * 4;
      sX[kk][c] = v.x; sX[kk][c + 1] = v.y; sX[kk][c + 2] = v.z; sX[kk][c + 3] = v.w;
    }
    __syncthreads();
#pragma unroll
    for (int kk = 0; kk < 32; ++kk) {
      float av[4], xv[Cw];
#pragma unroll
      for (int j = 0; j < 4; ++j) av[j] = sA[kk][ty * 4 + j];
#pragma unroll
      for (int q = 0; q < Cw; ++q) xv[q] = sX[kk][tx * Cw + q];
#pragma unroll
      for (int j = 0; j < 4; ++j)
#pragma unroll
        for (int q = 0; q < Cw; ++q) acc[j][q] += av[j] * xv[q];
    }
  }
#pragma unroll
  for (int j = 0; j < 4; ++j) {
    const int m = m0 + ty * 4 + j;
#pragma unroll
    for (int q = 0; q < Cw; ++q) {
      const int c = tx * Cw + q;
      size_t idx = ((size_t)b * N_ + m) * C + c;
      float v = alpha * acc[j][q];
      if (E) v += beta * E[idx];
      Y[idx] = v;
    }
  }
}

// ---------------------------------------------------------------------------
// Y[M,O] (+)= X[M,K] @ W^T  ; W rows of length ldw (>=K), optional bias
template <int K, int O>
__global__ __launch_bounds__(256) void rowgemm(const float* __restrict__ X,
                                               const float* __restrict__ W, int ldw,
                                               const float* __restrict__ bias,
                                               float* __restrict__ Y, int accumulate) {
  constexpr int Ow = O / 16;
  const int m0 = blockIdx.x * 64;
  const int tid = threadIdx.x;
  const int ty = tid >> 4, tx = tid & 15;
  __shared__ float sXm[32][68];     // [kk][m]
  __shared__ float sW[32][O + 4];   // [kk][o]
  float acc[4][Ow] = {};
  const int lm = tid >> 2, lk = (tid & 3) * 8;

  for (int k0 = 0; k0 < K; k0 += 32) {
    __syncthreads();
    {
      const float* p = X + (size_t)(m0 + lm) * K + k0 + lk;
      float4 v0 = *(const float4*)p;
      float4 v1 = *(const float4*)(p + 4);
      sXm[lk + 0][lm] = v0.x; sXm[lk + 1][lm] = v0.y;
      sXm[lk + 2][lm] = v0.z; sXm[lk + 3][lm] = v0.w;
      sXm[lk + 4][lm] = v1.x; sXm[lk + 5][lm] = v1.y;
      sXm[lk + 6][lm] = v1.z; sXm[lk + 7][lm] = v1.w;
    }
    for (int e = tid; e < 32 * O; e += 256) {
      int o = e >> 5, kk = e & 31;
      sW[kk][o] = W[(size_t)o * ldw + k0 + kk];
    }
    __syncthreads();
#pragma unroll
    for (int kk = 0; kk < 32; ++kk) {
      float a[4], w[Ow];
#pragma unroll
      for (int j = 0; j < 4; ++j) a[j] = sXm[kk][ty * 4 + j];
#pragma unroll
      for (int q = 0; q < Ow; ++q) w[q] = sW[kk][tx * Ow + q];
#pragma unroll
      for (int j = 0; j < 4; ++j)
#pragma unroll
        for (int q = 0; q < Ow; ++q) acc[j][q] += a[j] * w[q];
    }
  }
#pragma unroll
  for (int j = 0; j < 4; ++j) {
#pragma unroll
    for (int q = 0; q < Ow; ++q) {
      size_t idx = (size_t)(m0 + ty * 4 + j) * O + tx * Ow + q;
      if (accumulate) Y[idx] += acc[j][q];
      else Y[idx] = acc[j][q] + (bias ? bias[tx * Ow + q] : 0.f);
    }
  }
}

// ---------------------------------------------------------------------------
// Per-node dynamic-weight gconv:
// out[b,n,o] = sum_k sum_i xk[b,n,i] * (sum_d emb[n,d] wpool[d,k,i,o]) + emb[n,:]@bpool[:,o]
// one workgroup per node; weights generated chunk-wise into LDS
template <int O>
__global__ __launch_bounds__(256) void pernode(const float* __restrict__ xa,
                                               const float* __restrict__ xb,
                                               const float* __restrict__ xc,
                                               const float* __restrict__ emb,
                                               const float* __restrict__ wpool,
                                               const float* __restrict__ bpool,
                                               float* __restrict__ outp) {
  constexpr int Ow = O / 32;   // 4 (gate) or 2 (update)
  const int n = blockIdx.x;
  const int tid = threadIdx.x;
  __shared__ float sW[32][O + 4];   // [i_local][o]
  __shared__ float sX[32][68];      // [i_local][b]
  __shared__ float semb[16];
  if (tid < 16) semb[tid] = emb[n * 16 + tid];
  const int tx = tid & 31;          // o-group
  const int tb = tid >> 5;          // 0..7 -> 8 b's each
  const int lb = tid >> 2;          // 0..63
  const int li = (tid & 3) * 8;     // 0,8,16,24
  float acc[8][Ow] = {};

  for (int k = 0; k < 3; ++k) {
    const float* xk = (k == 0) ? xa : (k == 1 ? xb : xc);
    for (int i0 = 0; i0 < CIN_; i0 += 32) {
      __syncthreads();
      // generate weight chunk: sW[il][o] = sum_d emb[d] * wpool[d,k,i0+il,o]
      for (int e = tid; e < 32 * O; e += 256) {
        int il = e / O, o = e - il * O;
        const float* wp = wpool + ((size_t)k * CIN_ + i0 + il) * O + o;
        float s = 0.f;
#pragma unroll
        for (int d = 0; d < 16; ++d) s += semb[d] * wp[(size_t)d * 3 * CIN_ * O];
        sW[il][o] = s;
      }
      // stage x slice: sX[il][b] = xk[b, n, i0+il]
      {
        const float* p = xk + ((size_t)lb * N_ + n) * CIN_ + i0 + li;
        float4 v0 = *(const float4*)p;
        float4 v1 = *(const float4*)(p + 4);
        sX[li + 0][lb] = v0.x; sX[li + 1][lb] = v0.y;
        sX[li + 2][lb] = v0.z; sX[li + 3][lb] = v0.w;
        sX[li + 4][lb] = v1.x; sX[li + 5][lb] = v1.y;
        sX[li + 6][lb] = v1.z; sX[li + 7][lb] = v1.w;
      }
      __syncthreads();
#pragma unroll
      for (int il = 0; il < 32; ++il) {
        float xv[8], wv[Ow];
#pragma unroll
        for (int j = 0; j < 8; ++j) xv[j] = sX[il][tb * 8 + j];
#pragma unroll
        for (int q = 0; q < Ow; ++q) wv[q] = sW[il][tx * Ow + q];
#pragma unroll
        for (int j = 0; j < 8; ++j)
#pragma unroll
          for (int q = 0; q < Ow; ++q) acc[j][q] += xv[j] * wv[q];
      }
    }
  }
  // bias + store
  float bias[Ow];
#pragma unroll
  for (int q = 0; q < Ow; ++q) {
    int o = tx * Ow + q;
    float s = 0.f;
#pragma unroll
    for (int d = 0; d < 16; ++d) s += semb[d] * bpool[d * O + o];
    bias[q] = s;
  }
#pragma unroll
  for (int j = 0; j < 8; ++j)
#pragma unroll
    for (int q = 0; q < Ow; ++q)
      outp[((size_t)(tb * 8 + j) * N_ + n) * O + tx * Ow + q] = acc[j][q] + bias[q];
}

// ---------------------------------------------------------------------------
// SE attention scalars: for each b, s1 = sigmoid(relu(mean_n(leaky(A0))@w11^T)@w12^T),
// s2 likewise on A1. sout[0..63] = s1, sout[64..127] = s2.
template <int C, int HID>
__global__ __launch_bounds__(256) void att_scalars(const float* __restrict__ A0,
                                                   const float* __restrict__ A1,
                                                   const float* __restrict__ w11,
                                                   const float* __restrict__ w12,
                                                   const float* __restrict__ w21,
                                                   const float* __restrict__ w22,
                                                   float* __restrict__ sout) {
  constexpr int H = 256 / C;
  const int b = blockIdx.x;
  const int tid = threadIdx.x;
  const int c = tid % C, h = tid / C;
  __shared__ float r0[256], r1[256];
  __shared__ float sm0[C], sm1[C];
  __shared__ float h0[HID], h1[HID];
  const float* p0 = A0 + (size_t)b * N_ * C + c;
  const float* p1 = A1 + (size_t)b * N_ * C + c;
  float s0 = 0.f, s1 = 0.f;
  for (int n = h; n < N_; n += H) {
    s0 += lrelu(p0[(size_t)n * C]);
    s1 += lrelu(p1[(size_t)n * C]);
  }
  r0[tid] = s0; r1[tid] = s1;
  __syncthreads();
  if (h == 0) {
    for (int hh = 1; hh < H; ++hh) { s0 += r0[c + hh * C]; s1 += r1[c + hh * C]; }
    sm0[c] = s0 * (1.f / N_); sm1[c] = s1 * (1.f / N_);
  }
  __syncthreads();
  if (tid < HID) {
    float a = 0.f;
    for (int cc = 0; cc < C; ++cc) a += sm0[cc] * w11[tid * C + cc];
    h0[tid] = fmaxf(a, 0.f);
  } else if (tid >= 32 && tid < 32 + HID) {
    int j = tid - 32;
    float a = 0.f;
    for (int cc = 0; cc < C; ++cc) a += sm1[cc] * w21[j * C + cc];
    h1[j] = fmaxf(a, 0.f);
  }
  __syncthreads();
  if (tid == 0) {
    float a = 0.f;
    for (int j = 0; j < HID; ++j) a += h0[j] * w12[j];
    sout[b] = sigmoidf_(a);
  } else if (tid == 32) {
    float a = 0.f;
    for (int j = 0; j < HID; ++j) a += h1[j] * w22[j];
    sout[B_ + b] = sigmoidf_(a);
  }
}

// ---------------------------------------------------------------------------
// gate combine: z_r = sigmoid(s1*leaky(a0)+s2*leaky(a1)); cand=[x | z*state]; rbuf=r
__global__ __launch_bounds__(256) void gate_combine(const float* __restrict__ a0,
                                                    const float* __restrict__ a1,
                                                    const float* __restrict__ s12,
                                                    const float* __restrict__ x,
                                                    const float* __restrict__ st,
                                                    float* __restrict__ cand,
                                                    float* __restrict__ rbuf) {
  size_t t = (size_t)blockIdx.x * 256 + threadIdx.x;  // over B*N*64
  if (t >= (size_t)B_ * N_ * 64) return;
  int c = (int)(t & 63);
  size_t bn = t >> 6;
  int b = (int)(bn >> 10);
  float s1 = s12[b], s2 = s12[B_ + b];
  size_t i128 = bn * 128;
  float uz = s1 * lrelu(a0[i128 + c]) + s2 * lrelu(a1[i128 + c]);
  float ur = s1 * lrelu(a0[i128 + 64 + c]) + s2 * lrelu(a1[i128 + 64 + c]);
  float z = sigmoidf_(uz);
  float r = sigmoidf_(ur);
  cand[bn * CIN_ + 32 + c] = z * st[t];
  rbuf[t] = r;
  if (c < 32) cand[bn * CIN_ + c] = x[bn * 32 + c];
}

// final: hc = tanh(s1*leaky(a0)+s2*leaky(a1)); h = r*state + (1-r)*hc
__global__ __launch_bounds__(256) void final_h(const float* __restrict__ a0,
                                               const float* __restrict__ a1,
                                               const float* __restrict__ s12,
                                               const float* __restrict__ rbuf,
                                               const float* __restrict__ st,
                                               float* __restrict__ out) {
  size_t t = (size_t)blockIdx.x * 256 + threadIdx.x;  // over B*N*64
  if (t >= (size_t)B_ * N_ * 64) return;
  size_t bn = t >> 6;
  int b = (int)(bn >> 10);
  float s1 = s12[b], s2 = s12[B_ + b];
  float u = s1 * lrelu(a0[t]) + s2 * lrelu(a1[t]);
  float hc = tanhf(u);
  float r = rbuf[t];
  out[t] = r * st[t] + (1.f - r) * hc;
}

// ---------------------------------------------------------------------------
extern "C" void kernel_launch(void* const* d_in, const int* in_sizes, int n_in,
                              void* d_out, int out_size, void* d_ws, size_t ws_size,
                              hipStream_t stream) {
  const float* x       = (const float*)d_in[0];
  const float* state   = (const float*)d_in[1];
  const float* emb     = (const float*)d_in[2];
  const float* Ltil    = (const float*)d_in[3];
  const float* cheb    = (const float*)d_in[4];
  const float* g_wpool = (const float*)d_in[5];
  const float* g_bpool = (const float*)d_in[6];
  const float* g_iw    = (const float*)d_in[7];
  const float* g_ib    = (const float*)d_in[8];
  const float* g_gw    = (const float*)d_in[9];
  const float* g_gb    = (const float*)d_in[10];
  const float* g_a1w1  = (const float*)d_in[11];
  const float* g_a1w2  = (const float*)d_in[12];
  const float* g_a2w1  = (const float*)d_in[13];
  const float* g_a2w2  = (const float*)d_in[14];
  const float* u_wpool = (const float*)d_in[15];
  const float* u_bpool = (const float*)d_in[16];
  const float* u_iw    = (const float*)d_in[17];
  const float* u_ib    = (const float*)d_in[18];
  const float* u_gw    = (const float*)d_in[19];
  const float* u_gb    = (const float*)d_in[20];
  const float* u_a1w1  = (const float*)d_in[21];
  const float* u_a1w2  = (const float*)d_in[22];
  const float* u_a2w1  = (const float*)d_in[23];
  const float* u_a2w2  = (const float*)d_in[24];
  float* out = (float*)d_out;

  // workspace layout (floats); lifetimes allow gk->t1 region, rbuf->x0 upper half
  float* ws   = (float*)d_ws;
  float* inp  = ws;                    // [B,N,96]  6291456   (later reused as cand)
  float* t1   = inp  + 6291456;        // [B,N,96]
  float* t2   = t1   + 6291456;        // [B,N,96]
  float* x0   = t2   + 6291456;        // [B,N,128] 8388608   (update: x0u in lower half)
  float* acc0 = x0   + 8388608;        // [B,N,128]
  float* acc1 = acc0 + 8388608;        // [B,N,128]
  float* s12  = acc1 + 8388608;        // 128
  float* s12u = s12  + 128;            // 128
  float* gk   = t1;                    // aliases t1+t2 (dead once pernode done)
  float* rbuf = x0 + 4194304;          // upper half of x0 (gate-x0 dead by then)

  dim3 blk(256);
  dim3 gAdj(16, 64);

  // ---- gate AVWGCN (dim_out = 128) ----
  concat_xs<<<24576, blk, 0, stream>>>(x, state, inp);
  gemm_adj<96><<<gAdj, blk, 0, stream>>>(Ltil, inp, nullptr, t1, 1.f, 0.f);
  gemm_adj<96><<<gAdj, blk, 0, stream>>>(Ltil, t1, inp, t2, 2.f, -1.f);  // 2L^2x - x
  rowgemm<96, 128><<<1024, blk, 0, stream>>>(inp, g_iw, 96, g_ib, x0, 0);
  pernode<128><<<1024, blk, 0, stream>>>(inp, t1, t2, emb, g_wpool, g_bpool, acc0);
  for (int k = 0; k < 3; ++k) {
    gemm_adj<128><<<gAdj, blk, 0, stream>>>(cheb + (size_t)k * N_ * N_, x0, nullptr, gk, 1.f, 0.f);
    rowgemm<128, 128><<<1024, blk, 0, stream>>>(gk, g_gw + k * 128, 384,
                                                k == 0 ? g_gb : nullptr, acc1, k == 0 ? 0 : 1);
  }
  att_scalars<128, 8><<<64, blk, 0, stream>>>(acc0, acc1, g_a1w1, g_a1w2, g_a2w1, g_a2w2, s12);
  gate_combine<<<16384, blk, 0, stream>>>(acc0, acc1, s12, x, state, inp /*cand*/, rbuf);

  // ---- update AVWGCN (dim_out = 64), input = cand (in `inp`) ----
  gemm_adj<96><<<gAdj, blk, 0, stream>>>(Ltil, inp, nullptr, t1, 1.f, 0.f);
  gemm_adj<96><<<gAdj, blk, 0, stream>>>(Ltil, t1, inp, t2, 2.f, -1.f);
  rowgemm<96, 64><<<1024, blk, 0, stream>>>(inp, u_iw, 96, u_ib, x0, 0);
  pernode<64><<<1024, blk, 0, stream>>>(inp, t1, t2, emb, u_wpool, u_bpool, acc0);
  for (int k = 0; k < 3; ++k) {
    gemm_adj<64><<<gAdj, blk, 0, stream>>>(cheb + (size_t)k * N_ * N_, x0, nullptr, gk, 1.f, 0.f);
    rowgemm<64, 64><<<1024, blk, 0, stream>>>(gk, u_gw + k * 64, 192,
                                              k == 0 ? u_gb : nullptr, acc1, k == 0 ? 0 : 1);
  }
  att_scalars<64, 4><<<64, blk, 0, stream>>>(acc0, acc1, u_a1w1, u_a1w2, u_a2w1, u_a2w2, s12u);
  final_h<<<16384, blk, 0, stream>>>(acc0, acc1, s12u, rbuf, state, out);
}

// Round 2
// 2797.974 us; speedup vs baseline: 1.1901x; 1.1901x over previous
//
#include <hip/hip_runtime.h>
#include <hip/hip_bf16.h>
#include <math.h>

// RGSLCell: two AVWGCN blocks (gate 96->128, update 96->64) + SE-style scalar
// attention + GRU combine. B=64, N=1024, DIN=32, DOUT=64, K=3, ED=16, CIN=96.
// R2: per-node dynamic weights precomputed by a node-tiled GEMM (weightgen)
// into a bf16 workspace buffer; pernode2 streams them from global via LDS.
// R1 post-mortem: in-kernel weight gen re-read wpool 1024x in a latency-bound
// strided pattern (pernode 710us, VALUBusy 11%). weightgen reads wpool 16x.

#define B_  64
#define N_  1024
#define CIN_ 96
#define R_  288   // K*CIN = 3*96 rows of the per-node weight matrix

__device__ __forceinline__ float lrelu(float v) { return v >= 0.f ? v : 0.01f * v; }
__device__ __forceinline__ float sigmoidf_(float u) { return 1.f / (1.f + expf(-u)); }
__device__ __forceinline__ void unp2(unsigned u, float& a, float& b) {
  union { unsigned x; float f; } c, d;
  c.x = u << 16; d.x = u & 0xFFFF0000u; a = c.f; b = d.f;
}

// ---------------------------------------------------------------------------
// concat inp_state = [x | state]  -> [B,N,96]
__global__ __launch_bounds__(256) void concat_xs(const float* __restrict__ x,
                                                 const float* __restrict__ st,
                                                 float* __restrict__ inp) {
  size_t t = (size_t)blockIdx.x * 256 + threadIdx.x;
  if (t >= (size_t)B_ * N_ * CIN_) return;
  int i = (int)(t % CIN_);
  size_t bn = t / CIN_;
  inp[t] = (i < 32) ? x[bn * 32 + i] : st[bn * 64 + (i - 32)];
}

// ---------------------------------------------------------------------------
// W[n][r][o] (bf16) = sum_d emb[n][d] * wpool[d][r][o]
// grid: (R*O/256, 16 node-tiles); block 256. wpool read 16x total (not 1024x).
template <int O>
__global__ __launch_bounds__(256) void weightgen(const float* __restrict__ emb,
                                                 const float* __restrict__ wpool,
                                                 __hip_bfloat16* __restrict__ W) {
  const int tid = threadIdx.x;
  const int ro = blockIdx.x * 256 + tid;      // < R_*O
  const int n0 = blockIdx.y * 64;
  __shared__ float semb[64][17];
  for (int e = tid; e < 64 * 16; e += 256) semb[e >> 4][e & 15] = emb[(n0 + (e >> 4)) * 16 + (e & 15)];
  __syncthreads();
  float wv[16];
#pragma unroll
  for (int d = 0; d < 16; ++d) wv[d] = wpool[(size_t)d * R_ * O + ro];
#pragma unroll 4
  for (int n = 0; n < 64; ++n) {
    float s = 0.f;
#pragma unroll
    for (int d = 0; d < 16; ++d) s += semb[n][d] * wv[d];
    W[(size_t)(n0 + n) * R_ * O + ro] = __float2bfloat16(s);
  }
}

// ---------------------------------------------------------------------------
// Y[b] = alpha * (S @ X[b]) + beta * E[b]   (S: [1024,1024], X: [B,1024,C])
template <int C>
__global__ __launch_bounds__(256) void gemm_adj(const float* __restrict__ S,
                                                const float* __restrict__ X,
                                                const float* __restrict__ E,
                                                float* __restrict__ Y,
                                                float alpha, float beta) {
  constexpr int Cw = C / 16;
  const int b = blockIdx.y;
  const int m0 = blockIdx.x * 64;
  const int tid = threadIdx.x;
  const int ty = tid >> 4, tx = tid & 15;
  __shared__ float sA[32][68];
  __shared__ float sX[32][C + 4];
  float acc[4][Cw] = {};
  const float* Xb = X + (size_t)b * N_ * C;
  const int lm = tid >> 2;
  const int lk = (tid & 3) * 8;

  for (int k0 = 0; k0 < 1024; k0 += 32) {
    __syncthreads();
    {
      const float* p = S + (size_t)(m0 + lm) * 1024 + k0 + lk;
      float4 v0 = *(const float4*)p;
      float4 v1 = *(const float4*)(p + 4);
      sA[lk + 0][lm] = v0.x; sA[lk + 1][lm] = v0.y;
      sA[lk + 2][lm] = v0.z; sA[lk + 3][lm] = v0.w;
      sA[lk + 4][lm] = v1.x; sA[lk + 5][lm] = v1.y;
      sA[lk + 6][lm] = v1.z; sA[lk + 7][lm] = v1.w;
    }
    for (int e = tid; e < 8 * C; e += 256) {
      int kk = e / (C / 4), c4 = e % (C / 4);
      float4 v = *(const float4*)(Xb + (size_t)(k0 + kk) * C + c4 * 4);
      int c = c4 * 4;
      sX[kk][c] = v.x; sX[kk][c + 1] = v.y; sX[kk][c + 2] = v.z; sX[kk][c + 3] = v.w;
    }
    __syncthreads();
#pragma unroll
    for (int kk = 0; kk < 32; ++kk) {
      float av[4], xv[Cw];
#pragma unroll
      for (int j = 0; j < 4; ++j) av[j] = sA[kk][ty * 4 + j];
#pragma unroll
      for (int q = 0; q < Cw; ++q) xv[q] = sX[kk][tx * Cw + q];
#pragma unroll
      for (int j = 0; j < 4; ++j)
#pragma unroll
        for (int q = 0; q < Cw; ++q) acc[j][q] += av[j] * xv[q];
    }
  }
#pragma unroll
  for (int j = 0; j < 4; ++j) {
    const int m = m0 + ty * 4 + j;
#pragma unroll
    for (int q = 0; q < Cw; ++q) {
      const int c = tx * Cw + q;
      size_t idx = ((size_t)b * N_ + m) * C + c;
      float v = alpha * acc[j][q];
      if (E) v += beta * E[idx];
      Y[idx] = v;
    }
  }
}

// ---------------------------------------------------------------------------
// Y[M,O] (+)= X[M,K] @ W^T  ; W rows of length ldw (>=K), optional bias
template <int K, int O>
__global__ __launch_bounds__(256) void rowgemm(const float* __restrict__ X,
                                               const float* __restrict__ W, int ldw,
                                               const float* __restrict__ bias,
                                               float* __restrict__ Y, int accumulate) {
  constexpr int Ow = O / 16;
  const int m0 = blockIdx.x * 64;
  const int tid = threadIdx.x;
  const int ty = tid >> 4, tx = tid & 15;
  __shared__ float sXm[32][68];
  __shared__ float sW[32][O + 4];
  float acc[4][Ow] = {};
  const int lm = tid >> 2, lk = (tid & 3) * 8;

  for (int k0 = 0; k0 < K; k0 += 32) {
    __syncthreads();
    {
      const float* p = X + (size_t)(m0 + lm) * K + k0 + lk;
      float4 v0 = *(const float4*)p;
      float4 v1 = *(const float4*)(p + 4);
      sXm[lk + 0][lm] = v0.x; sXm[lk + 1][lm] = v0.y;
      sXm[lk + 2][lm] = v0.z; sXm[lk + 3][lm] = v0.w;
      sXm[lk + 4][lm] = v1.x; sXm[lk + 5][lm] = v1.y;
      sXm[lk + 6][lm] = v1.z; sXm[lk + 7][lm] = v1.w;
    }
    for (int e = tid; e < 32 * O; e += 256) {
      int o = e >> 5, kk = e & 31;
      sW[kk][o] = W[(size_t)o * ldw + k0 + kk];
    }
    __syncthreads();
#pragma unroll
    for (int kk = 0; kk < 32; ++kk) {
      float a[4], w[Ow];
#pragma unroll
      for (int j = 0; j < 4; ++j) a[j] = sXm[kk][ty * 4 + j];
#pragma unroll
      for (int q = 0; q < Ow; ++q) w[q] = sW[kk][tx * Ow + q];
#pragma unroll
      for (int j = 0; j < 4; ++j)
#pragma unroll
        for (int q = 0; q < Ow; ++q) acc[j][q] += a[j] * w[q];
    }
  }
#pragma unroll
  for (int j = 0; j < 4; ++j) {
#pragma unroll
    for (int q = 0; q < Ow; ++q) {
      size_t idx = (size_t)(m0 + ty * 4 + j) * O + tx * Ow + q;
      if (accumulate) Y[idx] += acc[j][q];
      else Y[idx] = acc[j][q] + (bias ? bias[tx * Ow + q] : 0.f);
    }
  }
}

// ---------------------------------------------------------------------------
// Per-node gconv with precomputed bf16 weights W[n][r][o], r = k*96+i.
// out[b,n,o] = sum_r xk[b,n,i] * W_n[r,o] + emb[n,:]@bpool[:,o]
template <int O>
__global__ __launch_bounds__(256) void pernode2(const float* __restrict__ xa,
                                                const float* __restrict__ xb,
                                                const float* __restrict__ xc,
                                                const __hip_bfloat16* __restrict__ W,
                                                const float* __restrict__ emb,
                                                const float* __restrict__ bpool,
                                                float* __restrict__ outp) {
  constexpr int Ow = O / 32;   // 4 (gate) or 2 (update)
  const int n = blockIdx.x;
  const int tid = threadIdx.x;
  __shared__ float sW[32][O + 4];   // [r_local][o]
  __shared__ float sX[32][68];      // [r_local][b]
  __shared__ float semb[16];
  if (tid < 16) semb[tid] = emb[n * 16 + tid];
  const int tx = tid & 31;          // o-group
  const int tb = tid >> 5;          // 0..7 -> 8 b's each
  const int lb = tid >> 2;          // 0..63
  const int li = (tid & 3) * 8;     // 0,8,16,24
  float acc[8][Ow] = {};
  const __hip_bfloat16* Wn = W + (size_t)n * R_ * O;

  for (int c = 0; c < 9; ++c) {     // chunk r0 = c*32; k = c/3, i0 = (c%3)*32
    const int k = c / 3, i0 = (c % 3) * 32;
    const float* xk = (k == 0) ? xa : (k == 1 ? xb : xc);
    __syncthreads();
    // stage W chunk bf16 -> fp32 LDS (coalesced uint4 = 8 bf16)
    for (int e = tid; e < 32 * O / 8; e += 256) {
      int row = e / (O / 8), o8 = (e % (O / 8)) * 8;
      uint4 v = *(const uint4*)(Wn + (size_t)(c * 32 + row) * O + o8);
      float f0, f1, f2, f3, f4, f5, f6, f7;
      unp2(v.x, f0, f1); unp2(v.y, f2, f3); unp2(v.z, f4, f5); unp2(v.w, f6, f7);
      sW[row][o8 + 0] = f0; sW[row][o8 + 1] = f1; sW[row][o8 + 2] = f2; sW[row][o8 + 3] = f3;
      sW[row][o8 + 4] = f4; sW[row][o8 + 5] = f5; sW[row][o8 + 6] = f6; sW[row][o8 + 7] = f7;
    }
    // stage x slice: sX[il][b] = xk[b, n, i0+il]
    {
      const float* p = xk + ((size_t)lb * N_ + n) * CIN_ + i0 + li;
      float4 v0 = *(const float4*)p;
      float4 v1 = *(const float4*)(p + 4);
      sX[li + 0][lb] = v0.x; sX[li + 1][lb] = v0.y;
      sX[li + 2][lb] = v0.z; sX[li + 3][lb] = v0.w;
      sX[li + 4][lb] = v1.x; sX[li + 5][lb] = v1.y;
      sX[li + 6][lb] = v1.z; sX[li + 7][lb] = v1.w;
    }
    __syncthreads();
#pragma unroll
    for (int il = 0; il < 32; ++il) {
      float xv[8], wv[Ow];
#pragma unroll
      for (int j = 0; j < 8; ++j) xv[j] = sX[il][tb * 8 + j];
#pragma unroll
      for (int q = 0; q < Ow; ++q) wv[q] = sW[il][tx * Ow + q];
#pragma unroll
      for (int j = 0; j < 8; ++j)
#pragma unroll
        for (int q = 0; q < Ow; ++q) acc[j][q] += xv[j] * wv[q];
    }
  }
  // bias + store
  float bias[Ow];
#pragma unroll
  for (int q = 0; q < Ow; ++q) {
    int o = tx * Ow + q;
    float s = 0.f;
#pragma unroll
    for (int d = 0; d < 16; ++d) s += semb[d] * bpool[d * O + o];
    bias[q] = s;
  }
#pragma unroll
  for (int j = 0; j < 8; ++j)
#pragma unroll
    for (int q = 0; q < Ow; ++q)
      outp[((size_t)(tb * 8 + j) * N_ + n) * O + tx * Ow + q] = acc[j][q] + bias[q];
}

// ---------------------------------------------------------------------------
// SE attention scalars
template <int C, int HID>
__global__ __launch_bounds__(256) void att_scalars(const float* __restrict__ A0,
                                                   const float* __restrict__ A1,
                                                   const float* __restrict__ w11,
                                                   const float* __restrict__ w12,
                                                   const float* __restrict__ w21,
                                                   const float* __restrict__ w22,
                                                   float* __restrict__ sout) {
  constexpr int H = 256 / C;
  const int b = blockIdx.x;
  const int tid = threadIdx.x;
  const int c = tid % C, h = tid / C;
  __shared__ float r0[256], r1[256];
  __shared__ float sm0[C], sm1[C];
  __shared__ float h0[HID], h1[HID];
  const float* p0 = A0 + (size_t)b * N_ * C + c;
  const float* p1 = A1 + (size_t)b * N_ * C + c;
  float s0 = 0.f, s1 = 0.f;
  for (int n = h; n < N_; n += H) {
    s0 += lrelu(p0[(size_t)n * C]);
    s1 += lrelu(p1[(size_t)n * C]);
  }
  r0[tid] = s0; r1[tid] = s1;
  __syncthreads();
  if (h == 0) {
    for (int hh = 1; hh < H; ++hh) { s0 += r0[c + hh * C]; s1 += r1[c + hh * C]; }
    sm0[c] = s0 * (1.f / N_); sm1[c] = s1 * (1.f / N_);
  }
  __syncthreads();
  if (tid < HID) {
    float a = 0.f;
    for (int cc = 0; cc < C; ++cc) a += sm0[cc] * w11[tid * C + cc];
    h0[tid] = fmaxf(a, 0.f);
  } else if (tid >= 32 && tid < 32 + HID) {
    int j = tid - 32;
    float a = 0.f;
    for (int cc = 0; cc < C; ++cc) a += sm1[cc] * w21[j * C + cc];
    h1[j] = fmaxf(a, 0.f);
  }
  __syncthreads();
  if (tid == 0) {
    float a = 0.f;
    for (int j = 0; j < HID; ++j) a += h0[j] * w12[j];
    sout[b] = sigmoidf_(a);
  } else if (tid == 32) {
    float a = 0.f;
    for (int j = 0; j < HID; ++j) a += h1[j] * w22[j];
    sout[B_ + b] = sigmoidf_(a);
  }
}

// ---------------------------------------------------------------------------
__global__ __launch_bounds__(256) void gate_combine(const float* __restrict__ a0,
                                                    const float* __restrict__ a1,
                                                    const float* __restrict__ s12,
                                                    const float* __restrict__ x,
                                                    const float* __restrict__ st,
                                                    float* __restrict__ cand,
                                                    float* __restrict__ rbuf) {
  size_t t = (size_t)blockIdx.x * 256 + threadIdx.x;  // over B*N*64
  if (t >= (size_t)B_ * N_ * 64) return;
  int c = (int)(t & 63);
  size_t bn = t >> 6;
  int b = (int)(bn >> 10);
  float s1 = s12[b], s2 = s12[B_ + b];
  size_t i128 = bn * 128;
  float uz = s1 * lrelu(a0[i128 + c]) + s2 * lrelu(a1[i128 + c]);
  float ur = s1 * lrelu(a0[i128 + 64 + c]) + s2 * lrelu(a1[i128 + 64 + c]);
  float z = sigmoidf_(uz);
  float r = sigmoidf_(ur);
  cand[bn * CIN_ + 32 + c] = z * st[t];
  rbuf[t] = r;
  if (c < 32) cand[bn * CIN_ + c] = x[bn * 32 + c];
}

__global__ __launch_bounds__(256) void final_h(const float* __restrict__ a0,
                                               const float* __restrict__ a1,
                                               const float* __restrict__ s12,
                                               const float* __restrict__ rbuf,
                                               const float* __restrict__ st,
                                               float* __restrict__ out) {
  size_t t = (size_t)blockIdx.x * 256 + threadIdx.x;  // over B*N*64
  if (t >= (size_t)B_ * N_ * 64) return;
  size_t bn = t >> 6;
  int b = (int)(bn >> 10);
  float s1 = s12[b], s2 = s12[B_ + b];
  float u = s1 * lrelu(a0[t]) + s2 * lrelu(a1[t]);
  float hc = tanhf(u);
  float r = rbuf[t];
  out[t] = r * st[t] + (1.f - r) * hc;
}

// ---------------------------------------------------------------------------
extern "C" void kernel_launch(void* const* d_in, const int* in_sizes, int n_in,
                              void* d_out, int out_size, void* d_ws, size_t ws_size,
                              hipStream_t stream) {
  const float* x       = (const float*)d_in[0];
  const float* state   = (const float*)d_in[1];
  const float* emb     = (const float*)d_in[2];
  const float* Ltil    = (const float*)d_in[3];
  const float* cheb    = (const float*)d_in[4];
  const float* g_wpool = (const float*)d_in[5];
  const float* g_bpool = (const float*)d_in[6];
  const float* g_iw    = (const float*)d_in[7];
  const float* g_ib    = (const float*)d_in[8];
  const float* g_gw    = (const float*)d_in[9];
  const float* g_gb    = (const float*)d_in[10];
  const float* g_a1w1  = (const float*)d_in[11];
  const float* g_a1w2  = (const float*)d_in[12];
  const float* g_a2w1  = (const float*)d_in[13];
  const float* g_a2w2  = (const float*)d_in[14];
  const float* u_wpool = (const float*)d_in[15];
  const float* u_bpool = (const float*)d_in[16];
  const float* u_iw    = (const float*)d_in[17];
  const float* u_ib    = (const float*)d_in[18];
  const float* u_gw    = (const float*)d_in[19];
  const float* u_gb    = (const float*)d_in[20];
  const float* u_a1w1  = (const float*)d_in[21];
  const float* u_a1w2  = (const float*)d_in[22];
  const float* u_a2w1  = (const float*)d_in[23];
  const float* u_a2w2  = (const float*)d_in[24];
  float* out = (float*)d_out;

  // workspace layout (floats)
  float* ws   = (float*)d_ws;
  float* inp  = ws;                    // [B,N,96]  6291456  (later reused as cand)
  float* t1   = inp  + 6291456;        // [B,N,96]
  float* t2   = t1   + 6291456;        // [B,N,96]
  float* x0   = t2   + 6291456;        // [B,N,128]
  float* acc0 = x0   + 8388608;        // [B,N,128]
  float* acc1 = acc0 + 8388608;        // [B,N,128]
  float* s12  = acc1 + 8388608;        // 128
  float* s12u = s12  + 128;            // 128
  __hip_bfloat16* Wbuf = (__hip_bfloat16*)(s12u + 128);  // [1024, 288, 128] bf16 max (75.5 MB)
  float* gk   = t1;                    // aliases t1/t2 (dead once pernode done)
  float* rbuf = x0 + 4194304;          // upper half of x0 (gate-x0 dead by then)

  dim3 blk(256);
  dim3 gAdj(16, 64);

  // ---- gate AVWGCN (dim_out = 128) ----
  weightgen<128><<<dim3(R_ * 128 / 256, 16), blk, 0, stream>>>(emb, g_wpool, Wbuf);
  concat_xs<<<24576, blk, 0, stream>>>(x, state, inp);
  gemm_adj<96><<<gAdj, blk, 0, stream>>>(Ltil, inp, nullptr, t1, 1.f, 0.f);
  gemm_adj<96><<<gAdj, blk, 0, stream>>>(Ltil, t1, inp, t2, 2.f, -1.f);  // 2L^2x - x
  rowgemm<96, 128><<<1024, blk, 0, stream>>>(inp, g_iw, 96, g_ib, x0, 0);
  pernode2<128><<<1024, blk, 0, stream>>>(inp, t1, t2, Wbuf, emb, g_bpool, acc0);
  for (int k = 0; k < 3; ++k) {
    gemm_adj<128><<<gAdj, blk, 0, stream>>>(cheb + (size_t)k * N_ * N_, x0, nullptr, gk, 1.f, 0.f);
    rowgemm<128, 128><<<1024, blk, 0, stream>>>(gk, g_gw + k * 128, 384,
                                                k == 0 ? g_gb : nullptr, acc1, k == 0 ? 0 : 1);
  }
  att_scalars<128, 8><<<64, blk, 0, stream>>>(acc0, acc1, g_a1w1, g_a1w2, g_a2w1, g_a2w2, s12);
  gate_combine<<<16384, blk, 0, stream>>>(acc0, acc1, s12, x, state, inp /*cand*/, rbuf);

  // ---- update AVWGCN (dim_out = 64), input = cand (in `inp`) ----
  weightgen<64><<<dim3(R_ * 64 / 256, 16), blk, 0, stream>>>(emb, u_wpool, Wbuf);
  gemm_adj<96><<<gAdj, blk, 0, stream>>>(Ltil, inp, nullptr, t1, 1.f, 0.f);
  gemm_adj<96><<<gAdj, blk, 0, stream>>>(Ltil, t1, inp, t2, 2.f, -1.f);
  rowgemm<96, 64><<<1024, blk, 0, stream>>>(inp, u_iw, 96, u_ib, x0, 0);
  pernode2<64><<<1024, blk, 0, stream>>>(inp, t1, t2, Wbuf, emb, u_bpool, acc0);
  for (int k = 0; k < 3; ++k) {
    gemm_adj<64><<<gAdj, blk, 0, stream>>>(cheb + (size_t)k * N_ * N_, x0, nullptr, gk, 1.f, 0.f);
    rowgemm<64, 64><<<1024, blk, 0, stream>>>(gk, u_gw + k * 64, 192,
                                              k == 0 ? u_gb : nullptr, acc1, k == 0 ? 0 : 1);
  }
  att_scalars<64, 4><<<64, blk, 0, stream>>>(acc0, acc1, u_a1w1, u_a1w2, u_a2w1, u_a2w2, s12u);
  final_h<<<16384, blk, 0, stream>>>(acc0, acc1, s12u, rbuf, state, out);
}

// Round 3
// 1160.287 us; speedup vs baseline: 2.8699x; 2.4114x over previous
//
#include <hip/hip_runtime.h>
#include <hip/hip_bf16.h>
#include <math.h>

// RGSLCell on MI355X. R3: bf16 MFMA for all adjacency GEMMs (S @ X, K=1024),
// node-major [n,b,c] activation layout, XOR-swizzled LDS + global_load_lds
// staging (m97 pattern). fp32 kept for: GEMM accum/outputs, pernode x inputs,
// rowgemm, attention, GRU combine. bf16 only: L/cheb, GEMM B-copies, pernode W.

#define B_  64
#define N_  1024
#define CIN_ 96
#define R_  288

typedef __attribute__((ext_vector_type(8))) short bf16x8;
typedef __attribute__((ext_vector_type(4))) float f32x4;
typedef unsigned short u16;
typedef unsigned int u32;

__device__ __forceinline__ float lrelu(float v) { return v >= 0.f ? v : 0.01f * v; }
__device__ __forceinline__ float sigmoidf_(float u) { return 1.f / (1.f + expf(-u)); }
__device__ __forceinline__ u16 f2b(float f) {
  __hip_bfloat16 h = __float2bfloat16(f);
  union { __hip_bfloat16 h; u16 u; } c; c.h = h; return c.u;
}
__device__ __forceinline__ float b2f(u16 u) {
  union { u32 x; float f; } c; c.x = ((u32)u) << 16; return c.f;
}
__device__ __forceinline__ void gload_lds16(const u16* gp, u16* lp) {
  __builtin_amdgcn_global_load_lds((const __attribute__((address_space(1))) u32*)gp,
                                   (__attribute__((address_space(3))) u32*)lp, 16, 0, 0);
}

// ---------------------------------------------------------------------------
// concat: inp[n][b][96] fp32 = [x | state]
__global__ __launch_bounds__(256) void concat_xs(const float* __restrict__ x,
                                                 const float* __restrict__ st,
                                                 float* __restrict__ inp) {
  size_t t = (size_t)blockIdx.x * 256 + threadIdx.x;
  if (t >= (size_t)B_ * N_ * CIN_) return;
  int i = (int)(t % CIN_);
  size_t v = t / CIN_;                 // v = n*64 + b
  size_t b = v & 63, n = v >> 6;
  inp[t] = (i < 32) ? x[(b * N_ + n) * 32 + i] : st[(b * N_ + n) * 64 + (i - 32)];
}

// fp32 -> bf16 flat convert (for L, cheb)
__global__ __launch_bounds__(256) void conv_f2b(const float* __restrict__ in,
                                                u16* __restrict__ out, int n4) {
  int t = blockIdx.x * 256 + threadIdx.x;
  if (t >= n4) return;
  float4 v = ((const float4*)in)[t];
  ushort4 o;
  o.x = f2b(v.x); o.y = f2b(v.y); o.z = f2b(v.z); o.w = f2b(v.w);
  ((ushort4*)out)[t] = o;
}

// transpose fp32 [1024 rows][J cols] -> bf16 [J][1024]  (GEMM B-operand copies)
__global__ __launch_bounds__(256) void transpose_f2b(const float* __restrict__ in,
                                                     u16* __restrict__ outT, int J) {
  __shared__ float t[32][33];
  const int tid = threadIdx.x;
  const int j0 = blockIdx.x * 32, r0 = blockIdx.y * 32;
  const int tc = tid & 31, tr = tid >> 5;
#pragma unroll
  for (int q = 0; q < 4; ++q)
    t[tr + q * 8][tc] = in[(size_t)(r0 + tr + q * 8) * J + j0 + tc];
  __syncthreads();
  const int jj = tid >> 3, rq = (tid & 7) * 4;
  ushort4 o;
  o.x = f2b(t[rq + 0][jj]); o.y = f2b(t[rq + 1][jj]);
  o.z = f2b(t[rq + 2][jj]); o.w = f2b(t[rq + 3][jj]);
  *(ushort4*)(outT + (size_t)(j0 + jj) * N_ + r0 + rq) = o;
}

// ---------------------------------------------------------------------------
// MFMA GEMM: Y[M][J] = alpha * (A @ B) + beta * E, A bf16 [M][1024] row-major,
// B given transposed bf16 Bt [J][1024]. 128x128 tile, BK=64, 16x16x32 bf16.
// XOR k-octet swizzle on the global fetch keeps LDS lane-contiguous for
// global_load_lds while making ds_read_b128 <=2-way bank conflicted.
__global__ __launch_bounds__(256) void mfma_gemm(const u16* __restrict__ A,
                                                 const u16* __restrict__ Bt,
                                                 const float* __restrict__ E,
                                                 float* __restrict__ Y,
                                                 int J, float alpha, float beta) {
  __shared__ u16 Asl[128 * 64];
  __shared__ u16 Bsl[128 * 64];
  const int tid = threadIdx.x;
  const int w = tid >> 6, lane = tid & 63;
  const int m0 = blockIdx.y * 128, n0 = blockIdx.x * 128;
  const int wr = w >> 1, wc = w & 1;
  const int sr = lane >> 3, so = lane & 7;   // staging: row-in-group, octet slot
  const int cl = lane & 15, q4 = lane >> 4;  // mfma lane coords
  f32x4 acc[4][4] = {};

  for (int k0 = 0; k0 < 1024; k0 += 64) {
    __syncthreads();
#pragma unroll
    for (int i = 0; i < 4; ++i) {
      const int r = i * 32 + w * 8 + sr;     // tile row 0..127 (lane-derived)
      const int o = so ^ (r & 7);            // swizzled k-octet to fetch
      gload_lds16(A + (size_t)(m0 + r) * 1024 + k0 + o * 8, Asl + (i * 32 + w * 8) * 64);
      gload_lds16(Bt + (size_t)(n0 + r) * 1024 + k0 + o * 8, Bsl + (i * 32 + w * 8) * 64);
    }
    __syncthreads();
#pragma unroll
    for (int kk = 0; kk < 2; ++kk) {
      bf16x8 af[4], bfr[4];
#pragma unroll
      for (int mi = 0; mi < 4; ++mi) {
        const int ra = wr * 64 + mi * 16 + cl;
        const int pos = (kk * 4 + q4) ^ (ra & 7);
        af[mi] = *(const bf16x8*)(Asl + ra * 64 + pos * 8);
      }
#pragma unroll
      for (int ni = 0; ni < 4; ++ni) {
        const int rb = wc * 64 + ni * 16 + cl;
        const int pos = (kk * 4 + q4) ^ (rb & 7);
        bfr[ni] = *(const bf16x8*)(Bsl + rb * 64 + pos * 8);
      }
#pragma unroll
      for (int mi = 0; mi < 4; ++mi)
#pragma unroll
        for (int ni = 0; ni < 4; ++ni)
          acc[mi][ni] = __builtin_amdgcn_mfma_f32_16x16x32_bf16(af[mi], bfr[ni], acc[mi][ni], 0, 0, 0);
    }
  }
  // epilogue: C/D layout col=lane&15, row=quad*4+reg (m89/m91 verified)
#pragma unroll
  for (int mi = 0; mi < 4; ++mi)
#pragma unroll
    for (int ni = 0; ni < 4; ++ni)
#pragma unroll
      for (int r = 0; r < 4; ++r) {
        const int m = m0 + wr * 64 + mi * 16 + q4 * 4 + r;
        const int n = n0 + wc * 64 + ni * 16 + cl;
        size_t idx = (size_t)m * J + n;
        float v = alpha * acc[mi][ni][r];
        if (E) v += beta * E[idx];
        Y[idx] = v;
      }
}

// ---------------------------------------------------------------------------
// Y[M,O] (+)= X[M,K] @ W^T  (fp32 VALU; X node-major flat rows)
template <int K, int O>
__global__ __launch_bounds__(256) void rowgemm(const float* __restrict__ X,
                                               const float* __restrict__ W, int ldw,
                                               const float* __restrict__ bias,
                                               float* __restrict__ Y, int accumulate) {
  constexpr int Ow = O / 16;
  const int m0 = blockIdx.x * 64;
  const int tid = threadIdx.x;
  const int ty = tid >> 4, tx = tid & 15;
  __shared__ float sXm[32][68];
  __shared__ float sW[32][O + 4];
  float acc[4][Ow] = {};
  const int lm = tid >> 2, lk = (tid & 3) * 8;

  for (int k0 = 0; k0 < K; k0 += 32) {
    __syncthreads();
    {
      const float* p = X + (size_t)(m0 + lm) * K + k0 + lk;
      float4 v0 = *(const float4*)p;
      float4 v1 = *(const float4*)(p + 4);
      sXm[lk + 0][lm] = v0.x; sXm[lk + 1][lm] = v0.y;
      sXm[lk + 2][lm] = v0.z; sXm[lk + 3][lm] = v0.w;
      sXm[lk + 4][lm] = v1.x; sXm[lk + 5][lm] = v1.y;
      sXm[lk + 6][lm] = v1.z; sXm[lk + 7][lm] = v1.w;
    }
    for (int e = tid; e < 32 * O; e += 256) {
      int o = e >> 5, kk = e & 31;
      sW[kk][o] = W[(size_t)o * ldw + k0 + kk];
    }
    __syncthreads();
#pragma unroll
    for (int kk = 0; kk < 32; ++kk) {
      float a[4], wv[Ow];
#pragma unroll
      for (int j = 0; j < 4; ++j) a[j] = sXm[kk][ty * 4 + j];
#pragma unroll
      for (int qq = 0; qq < Ow; ++qq) wv[qq] = sW[kk][tx * Ow + qq];
#pragma unroll
      for (int j = 0; j < 4; ++j)
#pragma unroll
        for (int qq = 0; qq < Ow; ++qq) acc[j][qq] += a[j] * wv[qq];
    }
  }
#pragma unroll
  for (int j = 0; j < 4; ++j)
#pragma unroll
    for (int qq = 0; qq < Ow; ++qq) {
      size_t idx = (size_t)(m0 + ty * 4 + j) * O + tx * Ow + qq;
      if (accumulate) Y[idx] += acc[j][qq];
      else Y[idx] = acc[j][qq] + (bias ? bias[tx * Ow + qq] : 0.f);
    }
}

// ---------------------------------------------------------------------------
// weightgen: W[n][r=288][64] bf16 = sum_d emb[n][d] * wpool[d][r][o0+o]
__global__ __launch_bounds__(256) void weightgen3(const float* __restrict__ emb,
                                                  const float* __restrict__ wpool,
                                                  int Otot, int o0, u16* __restrict__ W) {
  const int tid = threadIdx.x;
  const int ro = blockIdx.x * 256 + tid;      // < 288*64
  const int r = ro >> 6, o = ro & 63;
  const int n0 = blockIdx.y * 64;
  __shared__ float semb[64][17];
  for (int e = tid; e < 1024; e += 256) semb[e >> 4][e & 15] = emb[(n0 + (e >> 4)) * 16 + (e & 15)];
  __syncthreads();
  float wv[16];
#pragma unroll
  for (int d = 0; d < 16; ++d) wv[d] = wpool[((size_t)d * R_ + r) * Otot + o0 + o];
#pragma unroll 4
  for (int n = 0; n < 64; ++n) {
    float s = 0.f;
#pragma unroll
    for (int d = 0; d < 16; ++d) s += semb[n][d] * wv[d];
    W[(size_t)(n0 + n) * (R_ * 64) + ro] = f2b(s);
  }
}

// pernode: out[n][b][o0 + 0..63] (stride Otot) = sum_r x[n][b][i]*W_n[r][o] + bias
__global__ __launch_bounds__(256) void pernode3(const float* __restrict__ xa,
                                                const float* __restrict__ xb,
                                                const float* __restrict__ xc,
                                                const u16* __restrict__ W,
                                                const float* __restrict__ emb,
                                                const float* __restrict__ bpool,
                                                int Otot, int o0,
                                                float* __restrict__ outp) {
  const int n = blockIdx.x;
  const int tid = threadIdx.x;
  __shared__ float sW[32][68];
  __shared__ float sX[32][68];
  __shared__ float semb[16];
  if (tid < 16) semb[tid] = emb[n * 16 + tid];
  const int tx = tid & 31, tb = tid >> 5;
  const int lb = tid >> 2, li = (tid & 3) * 8;
  float acc[8][2] = {};
  const u16* Wn = W + (size_t)n * (R_ * 64);

  for (int c = 0; c < 9; ++c) {
    const int k = c / 3, i0 = (c % 3) * 32;
    const float* xk = (k == 0) ? xa : (k == 1 ? xb : xc);
    __syncthreads();
    {  // stage W chunk: rows c*32..+32, 64 o's; one uint4 (8 bf16) per thread
      const int row = tid >> 3, o8 = (tid & 7) * 8;
      uint4 v = *(const uint4*)(Wn + (size_t)(c * 32 + row) * 64 + o8);
      sW[row][o8 + 0] = b2f((u16)(v.x & 0xFFFF)); sW[row][o8 + 1] = b2f((u16)(v.x >> 16));
      sW[row][o8 + 2] = b2f((u16)(v.y & 0xFFFF)); sW[row][o8 + 3] = b2f((u16)(v.y >> 16));
      sW[row][o8 + 4] = b2f((u16)(v.z & 0xFFFF)); sW[row][o8 + 5] = b2f((u16)(v.z >> 16));
      sW[row][o8 + 6] = b2f((u16)(v.w & 0xFFFF)); sW[row][o8 + 7] = b2f((u16)(v.w >> 16));
    }
    {  // stage x slice (node-major: contiguous per node)
      const float* p = xk + ((size_t)n * B_ + lb) * CIN_ + i0 + li;
      float4 v0 = *(const float4*)p;
      float4 v1 = *(const float4*)(p + 4);
      sX[li + 0][lb] = v0.x; sX[li + 1][lb] = v0.y;
      sX[li + 2][lb] = v0.z; sX[li + 3][lb] = v0.w;
      sX[li + 4][lb] = v1.x; sX[li + 5][lb] = v1.y;
      sX[li + 6][lb] = v1.z; sX[li + 7][lb] = v1.w;
    }
    __syncthreads();
#pragma unroll
    for (int il = 0; il < 32; ++il) {
      float xv[8], wv[2];
#pragma unroll
      for (int j = 0; j < 8; ++j) xv[j] = sX[il][tb * 8 + j];
      wv[0] = sW[il][tx * 2]; wv[1] = sW[il][tx * 2 + 1];
#pragma unroll
      for (int j = 0; j < 8; ++j) { acc[j][0] += xv[j] * wv[0]; acc[j][1] += xv[j] * wv[1]; }
    }
  }
  float bias[2];
#pragma unroll
  for (int qq = 0; qq < 2; ++qq) {
    int o = o0 + tx * 2 + qq;
    float s = 0.f;
#pragma unroll
    for (int d = 0; d < 16; ++d) s += semb[d] * bpool[d * Otot + o];
    bias[qq] = s;
  }
#pragma unroll
  for (int j = 0; j < 8; ++j) {
    size_t base = ((size_t)n * B_ + tb * 8 + j) * Otot + o0 + tx * 2;
    outp[base] = acc[j][0] + bias[0];
    outp[base + 1] = acc[j][1] + bias[1];
  }
}

// ---------------------------------------------------------------------------
// SE attention scalars (node-major inputs [n][b][C])
template <int C, int HID>
__global__ __launch_bounds__(256) void att_scalars(const float* __restrict__ A0,
                                                   const float* __restrict__ A1,
                                                   const float* __restrict__ w11,
                                                   const float* __restrict__ w12,
                                                   const float* __restrict__ w21,
                                                   const float* __restrict__ w22,
                                                   float* __restrict__ sout) {
  constexpr int H = 256 / C;
  const int b = blockIdx.x;
  const int tid = threadIdx.x;
  const int c = tid % C, h = tid / C;
  __shared__ float r0[256], r1[256];
  __shared__ float sm0[C], sm1[C];
  __shared__ float h0[HID], h1[HID];
  const float* p0 = A0 + (size_t)b * C + c;
  const float* p1 = A1 + (size_t)b * C + c;
  float s0 = 0.f, s1 = 0.f;
  for (int n = h; n < N_; n += H) {
    s0 += lrelu(p0[(size_t)n * B_ * C]);
    s1 += lrelu(p1[(size_t)n * B_ * C]);
  }
  r0[tid] = s0; r1[tid] = s1;
  __syncthreads();
  if (h == 0) {
    for (int hh = 1; hh < H; ++hh) { s0 += r0[c + hh * C]; s1 += r1[c + hh * C]; }
    sm0[c] = s0 * (1.f / N_); sm1[c] = s1 * (1.f / N_);
  }
  __syncthreads();
  if (tid < HID) {
    float a = 0.f;
    for (int cc = 0; cc < C; ++cc) a += sm0[cc] * w11[tid * C + cc];
    h0[tid] = fmaxf(a, 0.f);
  } else if (tid >= 32 && tid < 32 + HID) {
    int j = tid - 32;
    float a = 0.f;
    for (int cc = 0; cc < C; ++cc) a += sm1[cc] * w21[j * C + cc];
    h1[j] = fmaxf(a, 0.f);
  }
  __syncthreads();
  if (tid == 0) {
    float a = 0.f;
    for (int j = 0; j < HID; ++j) a += h0[j] * w12[j];
    sout[b] = sigmoidf_(a);
  } else if (tid == 32) {
    float a = 0.f;
    for (int j = 0; j < HID; ++j) a += h1[j] * w22[j];
    sout[B_ + b] = sigmoidf_(a);
  }
}

// ---------------------------------------------------------------------------
// gate combine (node-major acc/cand/rbuf; x/state original [b][n][.] layout)
__global__ __launch_bounds__(256) void gate_combine(const float* __restrict__ a0,
                                                    const float* __restrict__ a1,
                                                    const float* __restrict__ s12,
                                                    const float* __restrict__ x,
                                                    const float* __restrict__ st,
                                                    float* __restrict__ cand,
                                                    float* __restrict__ rbuf) {
  size_t t = (size_t)blockIdx.x * 256 + threadIdx.x;  // over B*N*64
  if (t >= (size_t)B_ * N_ * 64) return;
  int c = (int)(t & 63);
  int b = (int)((t >> 6) & 63);
  int n = (int)(t >> 12);
  float s1 = s12[b], s2 = s12[B_ + b];
  size_t nb = (size_t)n * B_ + b;
  size_t i128 = nb * 128;
  float uz = s1 * lrelu(a0[i128 + c]) + s2 * lrelu(a1[i128 + c]);
  float ur = s1 * lrelu(a0[i128 + 64 + c]) + s2 * lrelu(a1[i128 + 64 + c]);
  float z = sigmoidf_(uz);
  float r = sigmoidf_(ur);
  float stv = st[((size_t)b * N_ + n) * 64 + c];
  cand[nb * CIN_ + 32 + c] = z * stv;
  rbuf[nb * 64 + c] = r;
  if (c < 32) cand[nb * CIN_ + c] = x[((size_t)b * N_ + n) * 32 + c];
}

// final: h = r*state + (1-r)*tanh(...)  -> out in original [b][n][64] layout
__global__ __launch_bounds__(256) void final_h(const float* __restrict__ a0,
                                               const float* __restrict__ a1,
                                               const float* __restrict__ s12,
                                               const float* __restrict__ rbuf,
                                               const float* __restrict__ st,
                                               float* __restrict__ out) {
  size_t t = (size_t)blockIdx.x * 256 + threadIdx.x;  // over B*N*64, t=b*65536+n*64+o
  if (t >= (size_t)B_ * N_ * 64) return;
  int o = (int)(t & 63);
  int n = (int)((t >> 6) & 1023);
  int b = (int)(t >> 16);
  float s1 = s12[b], s2 = s12[B_ + b];
  size_t nb = ((size_t)n * B_ + b) * 64 + o;
  float u = s1 * lrelu(a0[nb]) + s2 * lrelu(a1[nb]);
  float hc = tanhf(u);
  float r = rbuf[nb];
  out[t] = r * st[t] + (1.f - r) * hc;
}

// ---------------------------------------------------------------------------
extern "C" void kernel_launch(void* const* d_in, const int* in_sizes, int n_in,
                              void* d_out, int out_size, void* d_ws, size_t ws_size,
                              hipStream_t stream) {
  const float* x       = (const float*)d_in[0];
  const float* state   = (const float*)d_in[1];
  const float* emb     = (const float*)d_in[2];
  const float* Ltil    = (const float*)d_in[3];
  const float* cheb    = (const float*)d_in[4];
  const float* g_wpool = (const float*)d_in[5];
  const float* g_bpool = (const float*)d_in[6];
  const float* g_iw    = (const float*)d_in[7];
  const float* g_ib    = (const float*)d_in[8];
  const float* g_gw    = (const float*)d_in[9];
  const float* g_gb    = (const float*)d_in[10];
  const float* g_a1w1  = (const float*)d_in[11];
  const float* g_a1w2  = (const float*)d_in[12];
  const float* g_a2w1  = (const float*)d_in[13];
  const float* g_a2w2  = (const float*)d_in[14];
  const float* u_wpool = (const float*)d_in[15];
  const float* u_bpool = (const float*)d_in[16];
  const float* u_iw    = (const float*)d_in[17];
  const float* u_ib    = (const float*)d_in[18];
  const float* u_gw    = (const float*)d_in[19];
  const float* u_gb    = (const float*)d_in[20];
  const float* u_a1w1  = (const float*)d_in[21];
  const float* u_a1w2  = (const float*)d_in[22];
  const float* u_a2w1  = (const float*)d_in[23];
  const float* u_a2w2  = (const float*)d_in[24];
  float* out = (float*)d_out;

  // workspace layout (float offsets); total ~218 MB
  float* ws   = (float*)d_ws;
  float* inp  = ws;                     // [n,b,96]   6,291,456 (later cand)
  float* t1   = ws + 6291456;           // [n,b,96]
  float* t2   = ws + 12582912;          // [n,b,96]
  float* x0   = ws + 18874368;          // [n,b,128]  8,388,608
  float* acc1 = ws + 27262976;          // [n,b,128]  8,388,608
  float* acc0 = ws + 35651584;          // [n,b,128]  8,388,608
  u16*   Btp  = (u16*)(ws + 44040192);  // bf16 B-copies (<= 8192x1024)
  u16*   Lb   = (u16*)(ws + 48234496);  // bf16 L [1024][1024]
  u16*   chebb= (u16*)(ws + 48758784);  // bf16 cheb [3][1024][1024]
  float* s12  = ws + 50331648;          // 128
  float* s12u = ws + 50331776;          // 128
  float* rbuf = ws + 50331904;          // [n,b,64]   4,194,304
  // W overlays x0 (+1.05M spill into acc1): alive only weightgen->pernode,
  // both before x0/acc1 are written in each phase.
  u16*   Wbuf = (u16*)x0;               // [1024][288][64] bf16 = 9,437,184 floats
  float* gk   = t1;                     // cheb GEMM out, aliases t1/t2 (dead)

  dim3 blk(256);

  // ---- one-time converts ----
  conv_f2b<<<1024, blk, 0, stream>>>(Ltil, Lb, 262144);
  conv_f2b<<<3072, blk, 0, stream>>>(cheb, chebb, 786432);

  // ---- gate AVWGCN (dim_out = 128) ----
  concat_xs<<<24576, blk, 0, stream>>>(x, state, inp);
  transpose_f2b<<<dim3(192, 32), blk, 0, stream>>>(inp, Btp, 6144);
  mfma_gemm<<<dim3(48, 8), blk, 0, stream>>>(Lb, Btp, nullptr, t1, 6144, 1.f, 0.f);
  transpose_f2b<<<dim3(192, 32), blk, 0, stream>>>(t1, Btp, 6144);
  mfma_gemm<<<dim3(48, 8), blk, 0, stream>>>(Lb, Btp, inp, t2, 6144, 2.f, -1.f);
  for (int half = 0; half < 2; ++half) {
    weightgen3<<<dim3(72, 16), blk, 0, stream>>>(emb, g_wpool, 128, half * 64, Wbuf);
    pernode3<<<1024, blk, 0, stream>>>(inp, t1, t2, Wbuf, emb, g_bpool, 128, half * 64, acc0);
  }
  rowgemm<96, 128><<<1024, blk, 0, stream>>>(inp, g_iw, 96, g_ib, x0, 0);
  transpose_f2b<<<dim3(256, 32), blk, 0, stream>>>(x0, Btp, 8192);
  for (int k = 0; k < 3; ++k) {
    mfma_gemm<<<dim3(64, 8), blk, 0, stream>>>(chebb + (size_t)k * 1048576, Btp, nullptr, gk, 8192, 1.f, 0.f);
    rowgemm<128, 128><<<1024, blk, 0, stream>>>(gk, g_gw + k * 128, 384,
                                                k == 0 ? g_gb : nullptr, acc1, k == 0 ? 0 : 1);
  }
  att_scalars<128, 8><<<64, blk, 0, stream>>>(acc0, acc1, g_a1w1, g_a1w2, g_a2w1, g_a2w2, s12);
  gate_combine<<<16384, blk, 0, stream>>>(acc0, acc1, s12, x, state, inp /*cand*/, rbuf);

  // ---- update AVWGCN (dim_out = 64), input = cand (in `inp`) ----
  transpose_f2b<<<dim3(192, 32), blk, 0, stream>>>(inp, Btp, 6144);
  mfma_gemm<<<dim3(48, 8), blk, 0, stream>>>(Lb, Btp, nullptr, t1, 6144, 1.f, 0.f);
  transpose_f2b<<<dim3(192, 32), blk, 0, stream>>>(t1, Btp, 6144);
  mfma_gemm<<<dim3(48, 8), blk, 0, stream>>>(Lb, Btp, inp, t2, 6144, 2.f, -1.f);
  weightgen3<<<dim3(72, 16), blk, 0, stream>>>(emb, u_wpool, 64, 0, Wbuf);
  pernode3<<<1024, blk, 0, stream>>>(inp, t1, t2, Wbuf, emb, u_bpool, 64, 0, acc0);
  rowgemm<96, 64><<<1024, blk, 0, stream>>>(inp, u_iw, 96, u_ib, x0, 0);
  transpose_f2b<<<dim3(128, 32), blk, 0, stream>>>(x0, Btp, 4096);
  for (int k = 0; k < 3; ++k) {
    mfma_gemm<<<dim3(32, 8), blk, 0, stream>>>(chebb + (size_t)k * 1048576, Btp, nullptr, gk, 4096, 1.f, 0.f);
    rowgemm<64, 64><<<1024, blk, 0, stream>>>(gk, u_gw + k * 64, 192,
                                              k == 0 ? u_gb : nullptr, acc1, k == 0 ? 0 : 1);
  }
  att_scalars<64, 4><<<64, blk, 0, stream>>>(acc0, acc1, u_a1w1, u_a1w2, u_a2w1, u_a2w2, s12u);
  final_h<<<16384, blk, 0, stream>>>(acc0, acc1, s12u, rbuf, state, out);
}

// Round 4
// 1004.755 us; speedup vs baseline: 3.3141x; 1.1548x over previous
//
#include <hip/hip_runtime.h>
#include <hip/hip_bf16.h>
#include <math.h>

// RGSLCell on MI355X. R4: two-stage attention reduction (att_reduce 1024 blocks
// + att_finish). R3 post-mortem: att_scalars was latency-bound (64 blocks,
// VALUBusy 1.4%, 140us each). Rest unchanged from R3 (bf16 MFMA adjacency
// GEMMs, node-major layout, precomputed bf16 per-node weights).

#define B_  64
#define N_  1024
#define CIN_ 96
#define R_  288

typedef __attribute__((ext_vector_type(8))) short bf16x8;
typedef __attribute__((ext_vector_type(4))) float f32x4;
typedef unsigned short u16;
typedef unsigned int u32;

__device__ __forceinline__ float lrelu(float v) { return v >= 0.f ? v : 0.01f * v; }
__device__ __forceinline__ float sigmoidf_(float u) { return 1.f / (1.f + expf(-u)); }
__device__ __forceinline__ u16 f2b(float f) {
  __hip_bfloat16 h = __float2bfloat16(f);
  union { __hip_bfloat16 h; u16 u; } c; c.h = h; return c.u;
}
__device__ __forceinline__ float b2f(u16 u) {
  union { u32 x; float f; } c; c.x = ((u32)u) << 16; return c.f;
}
__device__ __forceinline__ void gload_lds16(const u16* gp, u16* lp) {
  __builtin_amdgcn_global_load_lds((const __attribute__((address_space(1))) u32*)gp,
                                   (__attribute__((address_space(3))) u32*)lp, 16, 0, 0);
}

// ---------------------------------------------------------------------------
// concat: inp[n][b][96] fp32 = [x | state]
__global__ __launch_bounds__(256) void concat_xs(const float* __restrict__ x,
                                                 const float* __restrict__ st,
                                                 float* __restrict__ inp) {
  size_t t = (size_t)blockIdx.x * 256 + threadIdx.x;
  if (t >= (size_t)B_ * N_ * CIN_) return;
  int i = (int)(t % CIN_);
  size_t v = t / CIN_;                 // v = n*64 + b
  size_t b = v & 63, n = v >> 6;
  inp[t] = (i < 32) ? x[(b * N_ + n) * 32 + i] : st[(b * N_ + n) * 64 + (i - 32)];
}

// fp32 -> bf16 flat convert (for L, cheb)
__global__ __launch_bounds__(256) void conv_f2b(const float* __restrict__ in,
                                                u16* __restrict__ out, int n4) {
  int t = blockIdx.x * 256 + threadIdx.x;
  if (t >= n4) return;
  float4 v = ((const float4*)in)[t];
  ushort4 o;
  o.x = f2b(v.x); o.y = f2b(v.y); o.z = f2b(v.z); o.w = f2b(v.w);
  ((ushort4*)out)[t] = o;
}

// transpose fp32 [1024 rows][J cols] -> bf16 [J][1024]  (GEMM B-operand copies)
__global__ __launch_bounds__(256) void transpose_f2b(const float* __restrict__ in,
                                                     u16* __restrict__ outT, int J) {
  __shared__ float t[32][33];
  const int tid = threadIdx.x;
  const int j0 = blockIdx.x * 32, r0 = blockIdx.y * 32;
  const int tc = tid & 31, tr = tid >> 5;
#pragma unroll
  for (int q = 0; q < 4; ++q)
    t[tr + q * 8][tc] = in[(size_t)(r0 + tr + q * 8) * J + j0 + tc];
  __syncthreads();
  const int jj = tid >> 3, rq = (tid & 7) * 4;
  ushort4 o;
  o.x = f2b(t[rq + 0][jj]); o.y = f2b(t[rq + 1][jj]);
  o.z = f2b(t[rq + 2][jj]); o.w = f2b(t[rq + 3][jj]);
  *(ushort4*)(outT + (size_t)(j0 + jj) * N_ + r0 + rq) = o;
}

// ---------------------------------------------------------------------------
// MFMA GEMM: Y[M][J] = alpha * (A @ B) + beta * E, A bf16 [M][1024] row-major,
// B given transposed bf16 Bt [J][1024]. 128x128 tile, BK=64, 16x16x32 bf16.
__global__ __launch_bounds__(256) void mfma_gemm(const u16* __restrict__ A,
                                                 const u16* __restrict__ Bt,
                                                 const float* __restrict__ E,
                                                 float* __restrict__ Y,
                                                 int J, float alpha, float beta) {
  __shared__ u16 Asl[128 * 64];
  __shared__ u16 Bsl[128 * 64];
  const int tid = threadIdx.x;
  const int w = tid >> 6, lane = tid & 63;
  const int m0 = blockIdx.y * 128, n0 = blockIdx.x * 128;
  const int wr = w >> 1, wc = w & 1;
  const int sr = lane >> 3, so = lane & 7;
  const int cl = lane & 15, q4 = lane >> 4;
  f32x4 acc[4][4] = {};

  for (int k0 = 0; k0 < 1024; k0 += 64) {
    __syncthreads();
#pragma unroll
    for (int i = 0; i < 4; ++i) {
      const int r = i * 32 + w * 8 + sr;
      const int o = so ^ (r & 7);
      gload_lds16(A + (size_t)(m0 + r) * 1024 + k0 + o * 8, Asl + (i * 32 + w * 8) * 64);
      gload_lds16(Bt + (size_t)(n0 + r) * 1024 + k0 + o * 8, Bsl + (i * 32 + w * 8) * 64);
    }
    __syncthreads();
#pragma unroll
    for (int kk = 0; kk < 2; ++kk) {
      bf16x8 af[4], bfr[4];
#pragma unroll
      for (int mi = 0; mi < 4; ++mi) {
        const int ra = wr * 64 + mi * 16 + cl;
        const int pos = (kk * 4 + q4) ^ (ra & 7);
        af[mi] = *(const bf16x8*)(Asl + ra * 64 + pos * 8);
      }
#pragma unroll
      for (int ni = 0; ni < 4; ++ni) {
        const int rb = wc * 64 + ni * 16 + cl;
        const int pos = (kk * 4 + q4) ^ (rb & 7);
        bfr[ni] = *(const bf16x8*)(Bsl + rb * 64 + pos * 8);
      }
#pragma unroll
      for (int mi = 0; mi < 4; ++mi)
#pragma unroll
        for (int ni = 0; ni < 4; ++ni)
          acc[mi][ni] = __builtin_amdgcn_mfma_f32_16x16x32_bf16(af[mi], bfr[ni], acc[mi][ni], 0, 0, 0);
    }
  }
#pragma unroll
  for (int mi = 0; mi < 4; ++mi)
#pragma unroll
    for (int ni = 0; ni < 4; ++ni)
#pragma unroll
      for (int r = 0; r < 4; ++r) {
        const int m = m0 + wr * 64 + mi * 16 + q4 * 4 + r;
        const int n = n0 + wc * 64 + ni * 16 + cl;
        size_t idx = (size_t)m * J + n;
        float v = alpha * acc[mi][ni][r];
        if (E) v += beta * E[idx];
        Y[idx] = v;
      }
}

// ---------------------------------------------------------------------------
// Y[M,O] (+)= X[M,K] @ W^T  (fp32 VALU)
template <int K, int O>
__global__ __launch_bounds__(256) void rowgemm(const float* __restrict__ X,
                                               const float* __restrict__ W, int ldw,
                                               const float* __restrict__ bias,
                                               float* __restrict__ Y, int accumulate) {
  constexpr int Ow = O / 16;
  const int m0 = blockIdx.x * 64;
  const int tid = threadIdx.x;
  const int ty = tid >> 4, tx = tid & 15;
  __shared__ float sXm[32][68];
  __shared__ float sW[32][O + 4];
  float acc[4][Ow] = {};
  const int lm = tid >> 2, lk = (tid & 3) * 8;

  for (int k0 = 0; k0 < K; k0 += 32) {
    __syncthreads();
    {
      const float* p = X + (size_t)(m0 + lm) * K + k0 + lk;
      float4 v0 = *(const float4*)p;
      float4 v1 = *(const float4*)(p + 4);
      sXm[lk + 0][lm] = v0.x; sXm[lk + 1][lm] = v0.y;
      sXm[lk + 2][lm] = v0.z; sXm[lk + 3][lm] = v0.w;
      sXm[lk + 4][lm] = v1.x; sXm[lk + 5][lm] = v1.y;
      sXm[lk + 6][lm] = v1.z; sXm[lk + 7][lm] = v1.w;
    }
    for (int e = tid; e < 32 * O; e += 256) {
      int o = e >> 5, kk = e & 31;
      sW[kk][o] = W[(size_t)o * ldw + k0 + kk];
    }
    __syncthreads();
#pragma unroll
    for (int kk = 0; kk < 32; ++kk) {
      float a[4], wv[Ow];
#pragma unroll
      for (int j = 0; j < 4; ++j) a[j] = sXm[kk][ty * 4 + j];
#pragma unroll
      for (int qq = 0; qq < Ow; ++qq) wv[qq] = sW[kk][tx * Ow + qq];
#pragma unroll
      for (int j = 0; j < 4; ++j)
#pragma unroll
        for (int qq = 0; qq < Ow; ++qq) acc[j][qq] += a[j] * wv[qq];
    }
  }
#pragma unroll
  for (int j = 0; j < 4; ++j)
#pragma unroll
    for (int qq = 0; qq < Ow; ++qq) {
      size_t idx = (size_t)(m0 + ty * 4 + j) * O + tx * Ow + qq;
      if (accumulate) Y[idx] += acc[j][qq];
      else Y[idx] = acc[j][qq] + (bias ? bias[tx * Ow + qq] : 0.f);
    }
}

// ---------------------------------------------------------------------------
// weightgen: W[n][r=288][64] bf16 = sum_d emb[n][d] * wpool[d][r][o0+o]
__global__ __launch_bounds__(256) void weightgen3(const float* __restrict__ emb,
                                                  const float* __restrict__ wpool,
                                                  int Otot, int o0, u16* __restrict__ W) {
  const int tid = threadIdx.x;
  const int ro = blockIdx.x * 256 + tid;
  const int r = ro >> 6, o = ro & 63;
  const int n0 = blockIdx.y * 64;
  __shared__ float semb[64][17];
  for (int e = tid; e < 1024; e += 256) semb[e >> 4][e & 15] = emb[(n0 + (e >> 4)) * 16 + (e & 15)];
  __syncthreads();
  float wv[16];
#pragma unroll
  for (int d = 0; d < 16; ++d) wv[d] = wpool[((size_t)d * R_ + r) * Otot + o0 + o];
#pragma unroll 4
  for (int n = 0; n < 64; ++n) {
    float s = 0.f;
#pragma unroll
    for (int d = 0; d < 16; ++d) s += semb[n][d] * wv[d];
    W[(size_t)(n0 + n) * (R_ * 64) + ro] = f2b(s);
  }
}

// pernode: out[n][b][o0 + 0..63] (stride Otot) = sum_r x[n][b][i]*W_n[r][o] + bias
__global__ __launch_bounds__(256) void pernode3(const float* __restrict__ xa,
                                                const float* __restrict__ xb,
                                                const float* __restrict__ xc,
                                                const u16* __restrict__ W,
                                                const float* __restrict__ emb,
                                                const float* __restrict__ bpool,
                                                int Otot, int o0,
                                                float* __restrict__ outp) {
  const int n = blockIdx.x;
  const int tid = threadIdx.x;
  __shared__ float sW[32][68];
  __shared__ float sX[32][68];
  __shared__ float semb[16];
  if (tid < 16) semb[tid] = emb[n * 16 + tid];
  const int tx = tid & 31, tb = tid >> 5;
  const int lb = tid >> 2, li = (tid & 3) * 8;
  float acc[8][2] = {};
  const u16* Wn = W + (size_t)n * (R_ * 64);

  for (int c = 0; c < 9; ++c) {
    const int k = c / 3, i0 = (c % 3) * 32;
    const float* xk = (k == 0) ? xa : (k == 1 ? xb : xc);
    __syncthreads();
    {
      const int row = tid >> 3, o8 = (tid & 7) * 8;
      uint4 v = *(const uint4*)(Wn + (size_t)(c * 32 + row) * 64 + o8);
      sW[row][o8 + 0] = b2f((u16)(v.x & 0xFFFF)); sW[row][o8 + 1] = b2f((u16)(v.x >> 16));
      sW[row][o8 + 2] = b2f((u16)(v.y & 0xFFFF)); sW[row][o8 + 3] = b2f((u16)(v.y >> 16));
      sW[row][o8 + 4] = b2f((u16)(v.z & 0xFFFF)); sW[row][o8 + 5] = b2f((u16)(v.z >> 16));
      sW[row][o8 + 6] = b2f((u16)(v.w & 0xFFFF)); sW[row][o8 + 7] = b2f((u16)(v.w >> 16));
    }
    {
      const float* p = xk + ((size_t)n * B_ + lb) * CIN_ + i0 + li;
      float4 v0 = *(const float4*)p;
      float4 v1 = *(const float4*)(p + 4);
      sX[li + 0][lb] = v0.x; sX[li + 1][lb] = v0.y;
      sX[li + 2][lb] = v0.z; sX[li + 3][lb] = v0.w;
      sX[li + 4][lb] = v1.x; sX[li + 5][lb] = v1.y;
      sX[li + 6][lb] = v1.z; sX[li + 7][lb] = v1.w;
    }
    __syncthreads();
#pragma unroll
    for (int il = 0; il < 32; ++il) {
      float xv[8], wv[2];
#pragma unroll
      for (int j = 0; j < 8; ++j) xv[j] = sX[il][tb * 8 + j];
      wv[0] = sW[il][tx * 2]; wv[1] = sW[il][tx * 2 + 1];
#pragma unroll
      for (int j = 0; j < 8; ++j) { acc[j][0] += xv[j] * wv[0]; acc[j][1] += xv[j] * wv[1]; }
    }
  }
  float bias[2];
#pragma unroll
  for (int qq = 0; qq < 2; ++qq) {
    int o = o0 + tx * 2 + qq;
    float s = 0.f;
#pragma unroll
    for (int d = 0; d < 16; ++d) s += semb[d] * bpool[d * Otot + o];
    bias[qq] = s;
  }
#pragma unroll
  for (int j = 0; j < 8; ++j) {
    size_t base = ((size_t)n * B_ + tb * 8 + j) * Otot + o0 + tx * 2;
    outp[base] = acc[j][0] + bias[0];
    outp[base + 1] = acc[j][1] + bias[1];
  }
}

// ---------------------------------------------------------------------------
// R4: two-stage attention mean. Stage 1: 16 n-chunks x 64 b blocks, float4
// coalesced, partial sums of lrelu into part0/part1 [b][16][C].
template <int C>
__global__ __launch_bounds__(256) void att_reduce(const float* __restrict__ A0,
                                                  const float* __restrict__ A1,
                                                  float* __restrict__ part0,
                                                  float* __restrict__ part1) {
  constexpr int C4 = C / 4;          // 32 (gate) / 16 (update)
  constexpr int H = 256 / C4;        // 8 / 16
  const int chunk = blockIdx.x;      // 0..15
  const int b = blockIdx.y;          // 0..63
  const int tid = threadIdx.x;
  const int c4 = tid % C4, h = tid / C4;
  __shared__ float4 r0[256], r1[256];
  float4 s0 = {0.f, 0.f, 0.f, 0.f}, s1 = {0.f, 0.f, 0.f, 0.f};
  const float4* p0 = (const float4*)(A0 + (size_t)b * C) + c4;
  const float4* p1 = (const float4*)(A1 + (size_t)b * C) + c4;
  const size_t stride = (size_t)B_ * C4;  // in float4 units
  for (int n = chunk * 64 + h; n < chunk * 64 + 64; n += H) {
    float4 v0 = p0[(size_t)n * stride];
    float4 v1 = p1[(size_t)n * stride];
    s0.x += lrelu(v0.x); s0.y += lrelu(v0.y); s0.z += lrelu(v0.z); s0.w += lrelu(v0.w);
    s1.x += lrelu(v1.x); s1.y += lrelu(v1.y); s1.z += lrelu(v1.z); s1.w += lrelu(v1.w);
  }
  r0[tid] = s0; r1[tid] = s1;
  __syncthreads();
  if (h == 0) {
    for (int hh = 1; hh < H; ++hh) {
      float4 a = r0[c4 + hh * C4], bb = r1[c4 + hh * C4];
      s0.x += a.x; s0.y += a.y; s0.z += a.z; s0.w += a.w;
      s1.x += bb.x; s1.y += bb.y; s1.z += bb.z; s1.w += bb.w;
    }
    ((float4*)(part0 + ((size_t)b * 16 + chunk) * C))[c4] = s0;
    ((float4*)(part1 + ((size_t)b * 16 + chunk) * C))[c4] = s1;
  }
}

// Stage 2: per-b MLP on the chunk-summed means.
template <int C, int HID>
__global__ __launch_bounds__(256) void att_finish(const float* __restrict__ part0,
                                                  const float* __restrict__ part1,
                                                  const float* __restrict__ w11,
                                                  const float* __restrict__ w12,
                                                  const float* __restrict__ w21,
                                                  const float* __restrict__ w22,
                                                  float* __restrict__ sout) {
  const int b = blockIdx.x;
  const int tid = threadIdx.x;
  __shared__ float sm0[C], sm1[C];
  __shared__ float h0[HID], h1[HID];
  if (tid < C) {
    float s0 = 0.f, s1 = 0.f;
    for (int ch = 0; ch < 16; ++ch) {
      s0 += part0[((size_t)b * 16 + ch) * C + tid];
      s1 += part1[((size_t)b * 16 + ch) * C + tid];
    }
    sm0[tid] = s0 * (1.f / N_); sm1[tid] = s1 * (1.f / N_);
  }
  __syncthreads();
  if (tid < HID) {
    float a = 0.f;
    for (int cc = 0; cc < C; ++cc) a += sm0[cc] * w11[tid * C + cc];
    h0[tid] = fmaxf(a, 0.f);
  } else if (tid >= 32 && tid < 32 + HID) {
    int j = tid - 32;
    float a = 0.f;
    for (int cc = 0; cc < C; ++cc) a += sm1[cc] * w21[j * C + cc];
    h1[j] = fmaxf(a, 0.f);
  }
  __syncthreads();
  if (tid == 0) {
    float a = 0.f;
    for (int j = 0; j < HID; ++j) a += h0[j] * w12[j];
    sout[b] = sigmoidf_(a);
  } else if (tid == 32) {
    float a = 0.f;
    for (int j = 0; j < HID; ++j) a += h1[j] * w22[j];
    sout[B_ + b] = sigmoidf_(a);
  }
}

// ---------------------------------------------------------------------------
__global__ __launch_bounds__(256) void gate_combine(const float* __restrict__ a0,
                                                    const float* __restrict__ a1,
                                                    const float* __restrict__ s12,
                                                    const float* __restrict__ x,
                                                    const float* __restrict__ st,
                                                    float* __restrict__ cand,
                                                    float* __restrict__ rbuf) {
  size_t t = (size_t)blockIdx.x * 256 + threadIdx.x;
  if (t >= (size_t)B_ * N_ * 64) return;
  int c = (int)(t & 63);
  int b = (int)((t >> 6) & 63);
  int n = (int)(t >> 12);
  float s1 = s12[b], s2 = s12[B_ + b];
  size_t nb = (size_t)n * B_ + b;
  size_t i128 = nb * 128;
  float uz = s1 * lrelu(a0[i128 + c]) + s2 * lrelu(a1[i128 + c]);
  float ur = s1 * lrelu(a0[i128 + 64 + c]) + s2 * lrelu(a1[i128 + 64 + c]);
  float z = sigmoidf_(uz);
  float r = sigmoidf_(ur);
  float stv = st[((size_t)b * N_ + n) * 64 + c];
  cand[nb * CIN_ + 32 + c] = z * stv;
  rbuf[nb * 64 + c] = r;
  if (c < 32) cand[nb * CIN_ + c] = x[((size_t)b * N_ + n) * 32 + c];
}

__global__ __launch_bounds__(256) void final_h(const float* __restrict__ a0,
                                               const float* __restrict__ a1,
                                               const float* __restrict__ s12,
                                               const float* __restrict__ rbuf,
                                               const float* __restrict__ st,
                                               float* __restrict__ out) {
  size_t t = (size_t)blockIdx.x * 256 + threadIdx.x;
  if (t >= (size_t)B_ * N_ * 64) return;
  int o = (int)(t & 63);
  int n = (int)((t >> 6) & 1023);
  int b = (int)(t >> 16);
  float s1 = s12[b], s2 = s12[B_ + b];
  size_t nb = ((size_t)n * B_ + b) * 64 + o;
  float u = s1 * lrelu(a0[nb]) + s2 * lrelu(a1[nb]);
  float hc = tanhf(u);
  float r = rbuf[nb];
  out[t] = r * st[t] + (1.f - r) * hc;
}

// ---------------------------------------------------------------------------
extern "C" void kernel_launch(void* const* d_in, const int* in_sizes, int n_in,
                              void* d_out, int out_size, void* d_ws, size_t ws_size,
                              hipStream_t stream) {
  const float* x       = (const float*)d_in[0];
  const float* state   = (const float*)d_in[1];
  const float* emb     = (const float*)d_in[2];
  const float* Ltil    = (const float*)d_in[3];
  const float* cheb    = (const float*)d_in[4];
  const float* g_wpool = (const float*)d_in[5];
  const float* g_bpool = (const float*)d_in[6];
  const float* g_iw    = (const float*)d_in[7];
  const float* g_ib    = (const float*)d_in[8];
  const float* g_gw    = (const float*)d_in[9];
  const float* g_gb    = (const float*)d_in[10];
  const float* g_a1w1  = (const float*)d_in[11];
  const float* g_a1w2  = (const float*)d_in[12];
  const float* g_a2w1  = (const float*)d_in[13];
  const float* g_a2w2  = (const float*)d_in[14];
  const float* u_wpool = (const float*)d_in[15];
  const float* u_bpool = (const float*)d_in[16];
  const float* u_iw    = (const float*)d_in[17];
  const float* u_ib    = (const float*)d_in[18];
  const float* u_gw    = (const float*)d_in[19];
  const float* u_gb    = (const float*)d_in[20];
  const float* u_a1w1  = (const float*)d_in[21];
  const float* u_a1w2  = (const float*)d_in[22];
  const float* u_a2w1  = (const float*)d_in[23];
  const float* u_a2w2  = (const float*)d_in[24];
  float* out = (float*)d_out;

  float* ws   = (float*)d_ws;
  float* inp  = ws;                     // [n,b,96]   6,291,456 (later cand)
  float* t1   = ws + 6291456;           // [n,b,96]
  float* t2   = ws + 12582912;          // [n,b,96]
  float* x0   = ws + 18874368;          // [n,b,128]
  float* acc1 = ws + 27262976;          // [n,b,128]
  float* acc0 = ws + 35651584;          // [n,b,128]
  u16*   Btp  = (u16*)(ws + 44040192);  // bf16 B-copies (<= 8192x1024)
  u16*   Lb   = (u16*)(ws + 48234496);  // bf16 L [1024][1024]
  u16*   chebb= (u16*)(ws + 48758784);  // bf16 cheb [3][1024][1024]
  float* s12  = ws + 50331648;          // 128
  float* s12u = ws + 50331776;          // 128
  float* rbuf = ws + 50331904;          // [n,b,64]   4,194,304
  float* part0= ws + 54526208;          // [64][16][128]
  float* part1= ws + 54657280;          // [64][16][128]
  u16*   Wbuf = (u16*)x0;               // overlays x0 (+spill into acc1 head)
  float* gk   = t1;

  dim3 blk(256);

  conv_f2b<<<1024, blk, 0, stream>>>(Ltil, Lb, 262144);
  conv_f2b<<<3072, blk, 0, stream>>>(cheb, chebb, 786432);

  // ---- gate AVWGCN (dim_out = 128) ----
  concat_xs<<<24576, blk, 0, stream>>>(x, state, inp);
  transpose_f2b<<<dim3(192, 32), blk, 0, stream>>>(inp, Btp, 6144);
  mfma_gemm<<<dim3(48, 8), blk, 0, stream>>>(Lb, Btp, nullptr, t1, 6144, 1.f, 0.f);
  transpose_f2b<<<dim3(192, 32), blk, 0, stream>>>(t1, Btp, 6144);
  mfma_gemm<<<dim3(48, 8), blk, 0, stream>>>(Lb, Btp, inp, t2, 6144, 2.f, -1.f);
  for (int half = 0; half < 2; ++half) {
    weightgen3<<<dim3(72, 16), blk, 0, stream>>>(emb, g_wpool, 128, half * 64, Wbuf);
    pernode3<<<1024, blk, 0, stream>>>(inp, t1, t2, Wbuf, emb, g_bpool, 128, half * 64, acc0);
  }
  rowgemm<96, 128><<<1024, blk, 0, stream>>>(inp, g_iw, 96, g_ib, x0, 0);
  transpose_f2b<<<dim3(256, 32), blk, 0, stream>>>(x0, Btp, 8192);
  for (int k = 0; k < 3; ++k) {
    mfma_gemm<<<dim3(64, 8), blk, 0, stream>>>(chebb + (size_t)k * 1048576, Btp, nullptr, gk, 8192, 1.f, 0.f);
    rowgemm<128, 128><<<1024, blk, 0, stream>>>(gk, g_gw + k * 128, 384,
                                                k == 0 ? g_gb : nullptr, acc1, k == 0 ? 0 : 1);
  }
  att_reduce<128><<<dim3(16, 64), blk, 0, stream>>>(acc0, acc1, part0, part1);
  att_finish<128, 8><<<64, blk, 0, stream>>>(part0, part1, g_a1w1, g_a1w2, g_a2w1, g_a2w2, s12);
  gate_combine<<<16384, blk, 0, stream>>>(acc0, acc1, s12, x, state, inp /*cand*/, rbuf);

  // ---- update AVWGCN (dim_out = 64) ----
  transpose_f2b<<<dim3(192, 32), blk, 0, stream>>>(inp, Btp, 6144);
  mfma_gemm<<<dim3(48, 8), blk, 0, stream>>>(Lb, Btp, nullptr, t1, 6144, 1.f, 0.f);
  transpose_f2b<<<dim3(192, 32), blk, 0, stream>>>(t1, Btp, 6144);
  mfma_gemm<<<dim3(48, 8), blk, 0, stream>>>(Lb, Btp, inp, t2, 6144, 2.f, -1.f);
  weightgen3<<<dim3(72, 16), blk, 0, stream>>>(emb, u_wpool, 64, 0, Wbuf);
  pernode3<<<1024, blk, 0, stream>>>(inp, t1, t2, Wbuf, emb, u_bpool, 64, 0, acc0);
  rowgemm<96, 64><<<1024, blk, 0, stream>>>(inp, u_iw, 96, u_ib, x0, 0);
  transpose_f2b<<<dim3(128, 32), blk, 0, stream>>>(x0, Btp, 4096);
  for (int k = 0; k < 3; ++k) {
    mfma_gemm<<<dim3(32, 8), blk, 0, stream>>>(chebb + (size_t)k * 1048576, Btp, nullptr, gk, 4096, 1.f, 0.f);
    rowgemm<64, 64><<<1024, blk, 0, stream>>>(gk, u_gw + k * 64, 192,
                                              k == 0 ? u_gb : nullptr, acc1, k == 0 ? 0 : 1);
  }
  att_reduce<64><<<dim3(16, 64), blk, 0, stream>>>(acc0, acc1, part0, part1);
  att_finish<64, 4><<<64, blk, 0, stream>>>(part0, part1, u_a1w1, u_a1w2, u_a2w1, u_a2w2, s12u);
  final_h<<<16384, blk, 0, stream>>>(acc0, acc1, s12u, rbuf, state, out);
}

// Round 5
// 863.868 us; speedup vs baseline: 3.8546x; 1.1631x over previous
//
#include <hip/hip_runtime.h>
#include <hip/hip_bf16.h>
#include <math.h>

// RGSLCell on MI355X. R5: cheb path restructured by associativity:
//   acc1 = sum_k cheb_k @ (x0 @ gw_k^T),  x0 = inp@iw^T+ib folded into V_k=gw_k*iw
//   -> Z = bf16(inp) @ V^T + b (MFMA, K=96) -> transpose -> single stacked-K
//      GEMM (K=3072) per phase. Removes all fp32 rowgemms + x0 + gk.
// R4 post-mortem: rowgemm tier was 8 dispatches x ~66/25us fp32 VALU-bound.

#define B_  64
#define N_  1024
#define CIN_ 96
#define R_  288

typedef __attribute__((ext_vector_type(8))) short bf16x8;
typedef __attribute__((ext_vector_type(4))) float f32x4;
typedef unsigned short u16;
typedef unsigned int u32;

__device__ __forceinline__ float lrelu(float v) { return v >= 0.f ? v : 0.01f * v; }
__device__ __forceinline__ float sigmoidf_(float u) { return 1.f / (1.f + expf(-u)); }
__device__ __forceinline__ u16 f2b(float f) {
  __hip_bfloat16 h = __float2bfloat16(f);
  union { __hip_bfloat16 h; u16 u; } c; c.h = h; return c.u;
}
__device__ __forceinline__ float b2f(u16 u) {
  union { u32 x; float f; } c; c.x = ((u32)u) << 16; return c.f;
}
__device__ __forceinline__ void gload_lds16(const u16* gp, u16* lp) {
  __builtin_amdgcn_global_load_lds((const __attribute__((address_space(1))) u32*)gp,
                                   (__attribute__((address_space(3))) u32*)lp, 16, 0, 0);
}

// ---------------------------------------------------------------------------
// concat: inp[n][b][96] fp32 = [x | state]
__global__ __launch_bounds__(256) void concat_xs(const float* __restrict__ x,
                                                 const float* __restrict__ st,
                                                 float* __restrict__ inp) {
  size_t t = (size_t)blockIdx.x * 256 + threadIdx.x;
  if (t >= (size_t)B_ * N_ * CIN_) return;
  int i = (int)(t % CIN_);
  size_t v = t / CIN_;
  size_t b = v & 63, n = v >> 6;
  inp[t] = (i < 32) ? x[(b * N_ + n) * 32 + i] : st[(b * N_ + n) * 64 + (i - 32)];
}

// fp32 -> bf16 flat convert
__global__ __launch_bounds__(256) void conv_f2b(const float* __restrict__ in,
                                                u16* __restrict__ out, int n4) {
  int t = blockIdx.x * 256 + threadIdx.x;
  if (t >= n4) return;
  float4 v = ((const float4*)in)[t];
  ushort4 o;
  o.x = f2b(v.x); o.y = f2b(v.y); o.z = f2b(v.z); o.w = f2b(v.w);
  ((ushort4*)out)[t] = o;
}

// transpose fp32 [1024 rows][J cols] -> bf16 [J][1024]  (L-path B-operand)
__global__ __launch_bounds__(256) void transpose_f2b(const float* __restrict__ in,
                                                     u16* __restrict__ outT, int J) {
  __shared__ float t[32][33];
  const int tid = threadIdx.x;
  const int j0 = blockIdx.x * 32, r0 = blockIdx.y * 32;
  const int tc = tid & 31, tr = tid >> 5;
#pragma unroll
  for (int q = 0; q < 4; ++q)
    t[tr + q * 8][tc] = in[(size_t)(r0 + tr + q * 8) * J + j0 + tc];
  __syncthreads();
  const int jj = tid >> 3, rq = (tid & 7) * 4;
  ushort4 o;
  o.x = f2b(t[rq + 0][jj]); o.y = f2b(t[rq + 1][jj]);
  o.z = f2b(t[rq + 2][jj]); o.w = f2b(t[rq + 3][jj]);
  *(ushort4*)(outT + (size_t)(j0 + jj) * N_ + r0 + rq) = o;
}

// ---------------------------------------------------------------------------
// MFMA GEMM (L-path): Y = alpha*(A@B) + beta*E; A bf16 [M][1024], Bt [J][1024]
__global__ __launch_bounds__(256) void mfma_gemm(const u16* __restrict__ A,
                                                 const u16* __restrict__ Bt,
                                                 const float* __restrict__ E,
                                                 float* __restrict__ Y,
                                                 int J, float alpha, float beta) {
  __shared__ u16 Asl[128 * 64];
  __shared__ u16 Bsl[128 * 64];
  const int tid = threadIdx.x;
  const int w = tid >> 6, lane = tid & 63;
  const int m0 = blockIdx.y * 128, n0 = blockIdx.x * 128;
  const int wr = w >> 1, wc = w & 1;
  const int sr = lane >> 3, so = lane & 7;
  const int cl = lane & 15, q4 = lane >> 4;
  f32x4 acc[4][4] = {};

  for (int k0 = 0; k0 < 1024; k0 += 64) {
    __syncthreads();
#pragma unroll
    for (int i = 0; i < 4; ++i) {
      const int r = i * 32 + w * 8 + sr;
      const int o = so ^ (r & 7);
      gload_lds16(A + (size_t)(m0 + r) * 1024 + k0 + o * 8, Asl + (i * 32 + w * 8) * 64);
      gload_lds16(Bt + (size_t)(n0 + r) * 1024 + k0 + o * 8, Bsl + (i * 32 + w * 8) * 64);
    }
    __syncthreads();
#pragma unroll
    for (int kk = 0; kk < 2; ++kk) {
      bf16x8 af[4], bfr[4];
#pragma unroll
      for (int mi = 0; mi < 4; ++mi) {
        const int ra = wr * 64 + mi * 16 + cl;
        af[mi] = *(const bf16x8*)(Asl + ra * 64 + ((kk * 4 + q4) ^ (ra & 7)) * 8);
      }
#pragma unroll
      for (int ni = 0; ni < 4; ++ni) {
        const int rb = wc * 64 + ni * 16 + cl;
        bfr[ni] = *(const bf16x8*)(Bsl + rb * 64 + ((kk * 4 + q4) ^ (rb & 7)) * 8);
      }
#pragma unroll
      for (int mi = 0; mi < 4; ++mi)
#pragma unroll
        for (int ni = 0; ni < 4; ++ni)
          acc[mi][ni] = __builtin_amdgcn_mfma_f32_16x16x32_bf16(af[mi], bfr[ni], acc[mi][ni], 0, 0, 0);
    }
  }
#pragma unroll
  for (int mi = 0; mi < 4; ++mi)
#pragma unroll
    for (int ni = 0; ni < 4; ++ni)
#pragma unroll
      for (int r = 0; r < 4; ++r) {
        const int m = m0 + wr * 64 + mi * 16 + q4 * 4 + r;
        const int n = n0 + wc * 64 + ni * 16 + cl;
        size_t idx = (size_t)m * J + n;
        float v = alpha * acc[mi][ni][r];
        if (E) v += beta * E[idx];
        Y[idx] = v;
      }
}

// ---------------------------------------------------------------------------
// vgen: V[c][i] = sum_j gw[o][k*O+j]*iw[j][i], b[c] = sum_j gw[o][k*O+j]*ib[j]
// c = k*O + o (o = c & (O-1), k = c >> oshift); rows c >= Ctot zero-padded.
__global__ __launch_bounds__(256) void vgen(const float* __restrict__ gw,
                                            const float* __restrict__ iw,
                                            const float* __restrict__ ib,
                                            int oshift, int Ctot,
                                            u16* __restrict__ Vb,
                                            float* __restrict__ ball) {
  __shared__ float siw[128 * 96];
  __shared__ float sib[128];
  const int O = 1 << oshift;
  const int c0 = blockIdx.x * 32;
  for (int e = threadIdx.x; e < O * 96; e += 256) siw[e] = iw[e];
  for (int e = threadIdx.x; e < O; e += 256) sib[e] = ib[e];
  __syncthreads();
  for (int idx = threadIdx.x; idx < 32 * 97; idx += 256) {
    int cl = idx / 97, col = idx - cl * 97;
    int c = c0 + cl;
    float s = 0.f;
    if (c < Ctot) {
      int o = c & (O - 1), k = c >> oshift;
      const float* g = gw + (size_t)o * (3 * O) + k * O;
      if (col < 96) { for (int j = 0; j < O; ++j) s += g[j] * siw[j * 96 + col]; }
      else          { for (int j = 0; j < O; ++j) s += g[j] * sib[j]; }
    }
    if (col < 96) Vb[(size_t)c * 96 + col] = f2b(s);
    else ball[c] = s;
  }
}

// ---------------------------------------------------------------------------
// zgemm: Z[M][Zs] bf16 = A[M][96] @ Vb^T + ball. 128x128 tile, BK=32 x 3.
__global__ __launch_bounds__(256) void zgemm(const u16* __restrict__ A,
                                             const u16* __restrict__ Bt,
                                             const float* __restrict__ ball,
                                             u16* __restrict__ Z, int Zs) {
  __shared__ u16 Asl[128 * 32];
  __shared__ u16 Bsl[128 * 32];
  const int tid = threadIdx.x;
  const int w = tid >> 6, lane = tid & 63;
  const int m0 = blockIdx.y * 128, n0 = blockIdx.x * 128;
  const int wr = w >> 1, wc = w & 1;
  const int sr = lane >> 2, so = lane & 3;   // 16 rows x 4 octets per wave
  const int cl = lane & 15, q4 = lane >> 4;
  f32x4 acc[4][4] = {};
  for (int k0 = 0; k0 < 96; k0 += 32) {
    __syncthreads();
#pragma unroll
    for (int i = 0; i < 2; ++i) {
      const int r = i * 64 + w * 16 + sr;
      const int o = so ^ (r & 3);
      gload_lds16(A + (size_t)(m0 + r) * 96 + k0 + o * 8, Asl + (i * 64 + w * 16) * 32);
      gload_lds16(Bt + (size_t)(n0 + r) * 96 + k0 + o * 8, Bsl + (i * 64 + w * 16) * 32);
    }
    __syncthreads();
    bf16x8 af[4], bfr[4];
#pragma unroll
    for (int mi = 0; mi < 4; ++mi) {
      const int ra = wr * 64 + mi * 16 + cl;
      af[mi] = *(const bf16x8*)(Asl + ra * 32 + (q4 ^ (ra & 3)) * 8);
    }
#pragma unroll
    for (int ni = 0; ni < 4; ++ni) {
      const int rb = wc * 64 + ni * 16 + cl;
      bfr[ni] = *(const bf16x8*)(Bsl + rb * 32 + (q4 ^ (rb & 3)) * 8);
    }
#pragma unroll
    for (int mi = 0; mi < 4; ++mi)
#pragma unroll
      for (int ni = 0; ni < 4; ++ni)
        acc[mi][ni] = __builtin_amdgcn_mfma_f32_16x16x32_bf16(af[mi], bfr[ni], acc[mi][ni], 0, 0, 0);
  }
#pragma unroll
  for (int mi = 0; mi < 4; ++mi)
#pragma unroll
    for (int ni = 0; ni < 4; ++ni) {
      const int c = n0 + wc * 64 + ni * 16 + cl;
      const float bb = ball[c];
#pragma unroll
      for (int r = 0; r < 4; ++r) {
        const int m = m0 + wr * 64 + mi * 16 + q4 * 4 + r;
        Z[(size_t)m * Zs + c] = f2b(acc[mi][ni][r] + bb);
      }
    }
}

// ---------------------------------------------------------------------------
// transpose Z [65536=(n*64+b)][Zs] bf16 -> Zt[b*Ctot + c][1024=n] bf16
__global__ __launch_bounds__(256) void transpose_b2b(const u16* __restrict__ Z, int Zs,
                                                     int Ctot, u16* __restrict__ Zt) {
  __shared__ u16 t[32][36];
  const int tid = threadIdx.x;
  const int c0 = blockIdx.x * 32, n0 = blockIdx.y * 32, b = blockIdx.z;
  {
    const int i = tid >> 3, c4 = (tid & 7) * 4;
    ushort4 v = *(const ushort4*)(Z + ((size_t)(n0 + i) * 64 + b) * Zs + c0 + c4);
    t[i][c4] = v.x; t[i][c4 + 1] = v.y; t[i][c4 + 2] = v.z; t[i][c4 + 3] = v.w;
  }
  __syncthreads();
  {
    const int c = tid >> 3, n4 = (tid & 7) * 4;
    ushort4 o;
    o.x = t[n4][c]; o.y = t[n4 + 1][c]; o.z = t[n4 + 2][c]; o.w = t[n4 + 3][c];
    *(ushort4*)(Zt + (size_t)(b * Ctot + c0 + c) * 1024 + n0 + n4) = o;
  }
}

// ---------------------------------------------------------------------------
// stacked-K cheb GEMM: Y[1024][J] = sum_kb cheb_kb @ Zt-slice + gb[j & omask]
// A3 = [3][1024][1024] bf16; Zt rows: (b*3 + kb)*O + oc, j = b*O + oc.
__global__ __launch_bounds__(256) void mfma_k3(const u16* __restrict__ A3,
                                               const u16* __restrict__ Zt,
                                               const float* __restrict__ gb,
                                               float* __restrict__ Y,
                                               int J, int obits) {
  __shared__ u16 Asl[128 * 64];
  __shared__ u16 Bsl[128 * 64];
  const int tid = threadIdx.x;
  const int w = tid >> 6, lane = tid & 63;
  const int m0 = blockIdx.y * 128, n0 = blockIdx.x * 128;
  const int wr = w >> 1, wc = w & 1;
  const int sr = lane >> 3, so = lane & 7;
  const int cl = lane & 15, q4 = lane >> 4;
  const int omask = (1 << obits) - 1;
  f32x4 acc[4][4] = {};

  for (int k0 = 0; k0 < 3072; k0 += 64) {
    const int kb = k0 >> 10, ko = k0 & 1023;
    __syncthreads();
#pragma unroll
    for (int i = 0; i < 4; ++i) {
      const int r = i * 32 + w * 8 + sr;
      const int o = so ^ (r & 7);
      gload_lds16(A3 + (size_t)kb * 1048576 + (size_t)(m0 + r) * 1024 + ko + o * 8,
                  Asl + (i * 32 + w * 8) * 64);
      const int jp = n0 + r;
      const int brow = (((jp >> obits) * 3 + kb) << obits) | (jp & omask);
      gload_lds16(Zt + (size_t)brow * 1024 + ko + o * 8, Bsl + (i * 32 + w * 8) * 64);
    }
    __syncthreads();
#pragma unroll
    for (int kk = 0; kk < 2; ++kk) {
      bf16x8 af[4], bfr[4];
#pragma unroll
      for (int mi = 0; mi < 4; ++mi) {
        const int ra = wr * 64 + mi * 16 + cl;
        af[mi] = *(const bf16x8*)(Asl + ra * 64 + ((kk * 4 + q4) ^ (ra & 7)) * 8);
      }
#pragma unroll
      for (int ni = 0; ni < 4; ++ni) {
        const int rb = wc * 64 + ni * 16 + cl;
        bfr[ni] = *(const bf16x8*)(Bsl + rb * 64 + ((kk * 4 + q4) ^ (rb & 7)) * 8);
      }
#pragma unroll
      for (int mi = 0; mi < 4; ++mi)
#pragma unroll
        for (int ni = 0; ni < 4; ++ni)
          acc[mi][ni] = __builtin_amdgcn_mfma_f32_16x16x32_bf16(af[mi], bfr[ni], acc[mi][ni], 0, 0, 0);
    }
  }
#pragma unroll
  for (int mi = 0; mi < 4; ++mi)
#pragma unroll
    for (int ni = 0; ni < 4; ++ni) {
      const int j = n0 + wc * 64 + ni * 16 + cl;
      const float bb = gb[j & omask];
#pragma unroll
      for (int r = 0; r < 4; ++r) {
        const int m = m0 + wr * 64 + mi * 16 + q4 * 4 + r;
        Y[(size_t)m * J + j] = acc[mi][ni][r] + bb;
      }
    }
}

// ---------------------------------------------------------------------------
// weightgen: W[n][r=288][64] bf16 = sum_d emb[n][d] * wpool[d][r][o0+o]
__global__ __launch_bounds__(256) void weightgen3(const float* __restrict__ emb,
                                                  const float* __restrict__ wpool,
                                                  int Otot, int o0, u16* __restrict__ W) {
  const int tid = threadIdx.x;
  const int ro = blockIdx.x * 256 + tid;
  const int r = ro >> 6, o = ro & 63;
  const int n0 = blockIdx.y * 64;
  __shared__ float semb[64][17];
  for (int e = tid; e < 1024; e += 256) semb[e >> 4][e & 15] = emb[(n0 + (e >> 4)) * 16 + (e & 15)];
  __syncthreads();
  float wv[16];
#pragma unroll
  for (int d = 0; d < 16; ++d) wv[d] = wpool[((size_t)d * R_ + r) * Otot + o0 + o];
#pragma unroll 4
  for (int n = 0; n < 64; ++n) {
    float s = 0.f;
#pragma unroll
    for (int d = 0; d < 16; ++d) s += semb[n][d] * wv[d];
    W[(size_t)(n0 + n) * (R_ * 64) + ro] = f2b(s);
  }
}

// pernode: out[n][b][o0 + 0..63] (stride Otot) = sum_r x[n][b][i]*W_n[r][o] + bias
__global__ __launch_bounds__(256) void pernode3(const float* __restrict__ xa,
                                                const float* __restrict__ xb,
                                                const float* __restrict__ xc,
                                                const u16* __restrict__ W,
                                                const float* __restrict__ emb,
                                                const float* __restrict__ bpool,
                                                int Otot, int o0,
                                                float* __restrict__ outp) {
  const int n = blockIdx.x;
  const int tid = threadIdx.x;
  __shared__ float sW[32][68];
  __shared__ float sX[32][68];
  __shared__ float semb[16];
  if (tid < 16) semb[tid] = emb[n * 16 + tid];
  const int tx = tid & 31, tb = tid >> 5;
  const int lb = tid >> 2, li = (tid & 3) * 8;
  float acc[8][2] = {};
  const u16* Wn = W + (size_t)n * (R_ * 64);

  for (int c = 0; c < 9; ++c) {
    const int k = c / 3, i0 = (c % 3) * 32;
    const float* xk = (k == 0) ? xa : (k == 1 ? xb : xc);
    __syncthreads();
    {
      const int row = tid >> 3, o8 = (tid & 7) * 8;
      uint4 v = *(const uint4*)(Wn + (size_t)(c * 32 + row) * 64 + o8);
      sW[row][o8 + 0] = b2f((u16)(v.x & 0xFFFF)); sW[row][o8 + 1] = b2f((u16)(v.x >> 16));
      sW[row][o8 + 2] = b2f((u16)(v.y & 0xFFFF)); sW[row][o8 + 3] = b2f((u16)(v.y >> 16));
      sW[row][o8 + 4] = b2f((u16)(v.z & 0xFFFF)); sW[row][o8 + 5] = b2f((u16)(v.z >> 16));
      sW[row][o8 + 6] = b2f((u16)(v.w & 0xFFFF)); sW[row][o8 + 7] = b2f((u16)(v.w >> 16));
    }
    {
      const float* p = xk + ((size_t)n * B_ + lb) * CIN_ + i0 + li;
      float4 v0 = *(const float4*)p;
      float4 v1 = *(const float4*)(p + 4);
      sX[li + 0][lb] = v0.x; sX[li + 1][lb] = v0.y;
      sX[li + 2][lb] = v0.z; sX[li + 3][lb] = v0.w;
      sX[li + 4][lb] = v1.x; sX[li + 5][lb] = v1.y;
      sX[li + 6][lb] = v1.z; sX[li + 7][lb] = v1.w;
    }
    __syncthreads();
#pragma unroll
    for (int il = 0; il < 32; ++il) {
      float xv[8], wv[2];
#pragma unroll
      for (int j = 0; j < 8; ++j) xv[j] = sX[il][tb * 8 + j];
      wv[0] = sW[il][tx * 2]; wv[1] = sW[il][tx * 2 + 1];
#pragma unroll
      for (int j = 0; j < 8; ++j) { acc[j][0] += xv[j] * wv[0]; acc[j][1] += xv[j] * wv[1]; }
    }
  }
  float bias[2];
#pragma unroll
  for (int qq = 0; qq < 2; ++qq) {
    int o = o0 + tx * 2 + qq;
    float s = 0.f;
#pragma unroll
    for (int d = 0; d < 16; ++d) s += semb[d] * bpool[d * Otot + o];
    bias[qq] = s;
  }
#pragma unroll
  for (int j = 0; j < 8; ++j) {
    size_t base = ((size_t)n * B_ + tb * 8 + j) * Otot + o0 + tx * 2;
    outp[base] = acc[j][0] + bias[0];
    outp[base + 1] = acc[j][1] + bias[1];
  }
}

// ---------------------------------------------------------------------------
// two-stage attention mean
template <int C>
__global__ __launch_bounds__(256) void att_reduce(const float* __restrict__ A0,
                                                  const float* __restrict__ A1,
                                                  float* __restrict__ part0,
                                                  float* __restrict__ part1) {
  constexpr int C4 = C / 4;
  constexpr int H = 256 / C4;
  const int chunk = blockIdx.x;
  const int b = blockIdx.y;
  const int tid = threadIdx.x;
  const int c4 = tid % C4, h = tid / C4;
  __shared__ float4 r0[256], r1[256];
  float4 s0 = {0.f, 0.f, 0.f, 0.f}, s1 = {0.f, 0.f, 0.f, 0.f};
  const float4* p0 = (const float4*)(A0 + (size_t)b * C) + c4;
  const float4* p1 = (const float4*)(A1 + (size_t)b * C) + c4;
  const size_t stride = (size_t)B_ * C4;
  for (int n = chunk * 64 + h; n < chunk * 64 + 64; n += H) {
    float4 v0 = p0[(size_t)n * stride];
    float4 v1 = p1[(size_t)n * stride];
    s0.x += lrelu(v0.x); s0.y += lrelu(v0.y); s0.z += lrelu(v0.z); s0.w += lrelu(v0.w);
    s1.x += lrelu(v1.x); s1.y += lrelu(v1.y); s1.z += lrelu(v1.z); s1.w += lrelu(v1.w);
  }
  r0[tid] = s0; r1[tid] = s1;
  __syncthreads();
  if (h == 0) {
    for (int hh = 1; hh < H; ++hh) {
      float4 a = r0[c4 + hh * C4], bb = r1[c4 + hh * C4];
      s0.x += a.x; s0.y += a.y; s0.z += a.z; s0.w += a.w;
      s1.x += bb.x; s1.y += bb.y; s1.z += bb.z; s1.w += bb.w;
    }
    ((float4*)(part0 + ((size_t)b * 16 + chunk) * C))[c4] = s0;
    ((float4*)(part1 + ((size_t)b * 16 + chunk) * C))[c4] = s1;
  }
}

template <int C, int HID>
__global__ __launch_bounds__(256) void att_finish(const float* __restrict__ part0,
                                                  const float* __restrict__ part1,
                                                  const float* __restrict__ w11,
                                                  const float* __restrict__ w12,
                                                  const float* __restrict__ w21,
                                                  const float* __restrict__ w22,
                                                  float* __restrict__ sout) {
  const int b = blockIdx.x;
  const int tid = threadIdx.x;
  __shared__ float sm0[C], sm1[C];
  __shared__ float h0[HID], h1[HID];
  if (tid < C) {
    float s0 = 0.f, s1 = 0.f;
    for (int ch = 0; ch < 16; ++ch) {
      s0 += part0[((size_t)b * 16 + ch) * C + tid];
      s1 += part1[((size_t)b * 16 + ch) * C + tid];
    }
    sm0[tid] = s0 * (1.f / N_); sm1[tid] = s1 * (1.f / N_);
  }
  __syncthreads();
  if (tid < HID) {
    float a = 0.f;
    for (int cc = 0; cc < C; ++cc) a += sm0[cc] * w11[tid * C + cc];
    h0[tid] = fmaxf(a, 0.f);
  } else if (tid >= 32 && tid < 32 + HID) {
    int j = tid - 32;
    float a = 0.f;
    for (int cc = 0; cc < C; ++cc) a += sm1[cc] * w21[j * C + cc];
    h1[j] = fmaxf(a, 0.f);
  }
  __syncthreads();
  if (tid == 0) {
    float a = 0.f;
    for (int j = 0; j < HID; ++j) a += h0[j] * w12[j];
    sout[b] = sigmoidf_(a);
  } else if (tid == 32) {
    float a = 0.f;
    for (int j = 0; j < HID; ++j) a += h1[j] * w22[j];
    sout[B_ + b] = sigmoidf_(a);
  }
}

// ---------------------------------------------------------------------------
__global__ __launch_bounds__(256) void gate_combine(const float* __restrict__ a0,
                                                    const float* __restrict__ a1,
                                                    const float* __restrict__ s12,
                                                    const float* __restrict__ x,
                                                    const float* __restrict__ st,
                                                    float* __restrict__ cand,
                                                    float* __restrict__ rbuf) {
  size_t t = (size_t)blockIdx.x * 256 + threadIdx.x;
  if (t >= (size_t)B_ * N_ * 64) return;
  int c = (int)(t & 63);
  int b = (int)((t >> 6) & 63);
  int n = (int)(t >> 12);
  float s1 = s12[b], s2 = s12[B_ + b];
  size_t nb = (size_t)n * B_ + b;
  size_t i128 = nb * 128;
  float uz = s1 * lrelu(a0[i128 + c]) + s2 * lrelu(a1[i128 + c]);
  float ur = s1 * lrelu(a0[i128 + 64 + c]) + s2 * lrelu(a1[i128 + 64 + c]);
  float z = sigmoidf_(uz);
  float r = sigmoidf_(ur);
  float stv = st[((size_t)b * N_ + n) * 64 + c];
  cand[nb * CIN_ + 32 + c] = z * stv;
  rbuf[nb * 64 + c] = r;
  if (c < 32) cand[nb * CIN_ + c] = x[((size_t)b * N_ + n) * 32 + c];
}

__global__ __launch_bounds__(256) void final_h(const float* __restrict__ a0,
                                               const float* __restrict__ a1,
                                               const float* __restrict__ s12,
                                               const float* __restrict__ rbuf,
                                               const float* __restrict__ st,
                                               float* __restrict__ out) {
  size_t t = (size_t)blockIdx.x * 256 + threadIdx.x;
  if (t >= (size_t)B_ * N_ * 64) return;
  int o = (int)(t & 63);
  int n = (int)((t >> 6) & 1023);
  int b = (int)(t >> 16);
  float s1 = s12[b], s2 = s12[B_ + b];
  size_t nb = ((size_t)n * B_ + b) * 64 + o;
  float u = s1 * lrelu(a0[nb]) + s2 * lrelu(a1[nb]);
  float hc = tanhf(u);
  float r = rbuf[nb];
  out[t] = r * st[t] + (1.f - r) * hc;
}

// ---------------------------------------------------------------------------
extern "C" void kernel_launch(void* const* d_in, const int* in_sizes, int n_in,
                              void* d_out, int out_size, void* d_ws, size_t ws_size,
                              hipStream_t stream) {
  const float* x       = (const float*)d_in[0];
  const float* state   = (const float*)d_in[1];
  const float* emb     = (const float*)d_in[2];
  const float* Ltil    = (const float*)d_in[3];
  const float* cheb    = (const float*)d_in[4];
  const float* g_wpool = (const float*)d_in[5];
  const float* g_bpool = (const float*)d_in[6];
  const float* g_iw    = (const float*)d_in[7];
  const float* g_ib    = (const float*)d_in[8];
  const float* g_gw    = (const float*)d_in[9];
  const float* g_gb    = (const float*)d_in[10];
  const float* g_a1w1  = (const float*)d_in[11];
  const float* g_a1w2  = (const float*)d_in[12];
  const float* g_a2w1  = (const float*)d_in[13];
  const float* g_a2w2  = (const float*)d_in[14];
  const float* u_wpool = (const float*)d_in[15];
  const float* u_bpool = (const float*)d_in[16];
  const float* u_iw    = (const float*)d_in[17];
  const float* u_ib    = (const float*)d_in[18];
  const float* u_gw    = (const float*)d_in[19];
  const float* u_gb    = (const float*)d_in[20];
  const float* u_a1w1  = (const float*)d_in[21];
  const float* u_a1w2  = (const float*)d_in[22];
  const float* u_a2w1  = (const float*)d_in[23];
  const float* u_a2w2  = (const float*)d_in[24];
  float* out = (float*)d_out;

  // workspace (float offsets), ~232 MB total (277 MB proven in R2).
  float* ws   = (float*)d_ws;
  float* inp  = ws;                       // [n,b,96] 6,291,456 (later cand)
  float* t1   = ws + 6291456;             // [n,b,96]
  float* t2   = ws + 12582912;            // [n,b,96]
  u16*   Wbuf = (u16*)(ws + 18874368);    // [1024][288][64] bf16 = 9,437,184 fl
  u16*   Btp  = (u16*)(ws + 28311552);    // [6144][1024] bf16 = 3,145,728 fl
  float* acc1 = ws + 31457280;            // [n,b,128]
  float* acc0 = ws + 39845888;            // [n,b,128]
  u16*   Lb   = (u16*)(ws + 48234496);    // [1024][1024] bf16
  u16*   chebb= (u16*)(ws + 48758784);    // [3][1024][1024] bf16
  float* s12  = ws + 50331648;
  float* s12u = ws + 50331776;
  float* part0= ws + 50331904;            // [64][16][128]
  float* part1= ws + 50462976;
  float* rbuf = ws + 50594048;            // [n,b,64] 4,194,304
  u16*   inpb = (u16*)(ws + 54788352);    // [65536][96] bf16 = 3,145,728 fl
  u16*   Vbg  = (u16*)(ws + 57934080);    // [384][96] bf16
  float* bag  = ws + 57953280;            // [384]
  u16*   Vbu  = (u16*)(ws + 57953664);    // [256][96] bf16
  float* bau  = ws + 57966336;            // [256]
  // overlays (exact-fit, lifetime-checked):
  u16*   Z    = (u16*)t1;                 // gate [65536][384], upd [65536][256]
  u16*   Zt   = (u16*)Wbuf;               // gate [24576][1024], upd [12288][1024]

  dim3 blk(256);

  conv_f2b<<<1024, blk, 0, stream>>>(Ltil, Lb, 262144);
  conv_f2b<<<3072, blk, 0, stream>>>(cheb, chebb, 786432);

  // ---- gate AVWGCN (dim_out = 128) ----
  concat_xs<<<24576, blk, 0, stream>>>(x, state, inp);
  conv_f2b<<<6144, blk, 0, stream>>>(inp, inpb, 1572864);
  transpose_f2b<<<dim3(192, 32), blk, 0, stream>>>(inp, Btp, 6144);
  mfma_gemm<<<dim3(48, 8), blk, 0, stream>>>(Lb, Btp, nullptr, t1, 6144, 1.f, 0.f);
  transpose_f2b<<<dim3(192, 32), blk, 0, stream>>>(t1, Btp, 6144);
  mfma_gemm<<<dim3(48, 8), blk, 0, stream>>>(Lb, Btp, inp, t2, 6144, 2.f, -1.f);
  vgen<<<12, blk, 0, stream>>>(g_gw, g_iw, g_ib, 7, 384, Vbg, bag);
  for (int half = 0; half < 2; ++half) {
    weightgen3<<<dim3(72, 16), blk, 0, stream>>>(emb, g_wpool, 128, half * 64, Wbuf);
    pernode3<<<1024, blk, 0, stream>>>(inp, t1, t2, Wbuf, emb, g_bpool, 128, half * 64, acc0);
  }
  zgemm<<<dim3(3, 512), blk, 0, stream>>>(inpb, Vbg, bag, Z, 384);     // overwrites t1/t2
  transpose_b2b<<<dim3(12, 32, 64), blk, 0, stream>>>(Z, 384, 384, Zt); // overwrites Wbuf/Btp
  mfma_k3<<<dim3(64, 8), blk, 0, stream>>>(chebb, Zt, g_gb, acc1, 8192, 7);
  att_reduce<128><<<dim3(16, 64), blk, 0, stream>>>(acc0, acc1, part0, part1);
  att_finish<128, 8><<<64, blk, 0, stream>>>(part0, part1, g_a1w1, g_a1w2, g_a2w1, g_a2w2, s12);
  gate_combine<<<16384, blk, 0, stream>>>(acc0, acc1, s12, x, state, inp /*cand*/, rbuf);

  // ---- update AVWGCN (dim_out = 64) ----
  conv_f2b<<<6144, blk, 0, stream>>>(inp, inpb, 1572864);
  transpose_f2b<<<dim3(192, 32), blk, 0, stream>>>(inp, Btp, 6144);
  mfma_gemm<<<dim3(48, 8), blk, 0, stream>>>(Lb, Btp, nullptr, t1, 6144, 1.f, 0.f);
  transpose_f2b<<<dim3(192, 32), blk, 0, stream>>>(t1, Btp, 6144);
  mfma_gemm<<<dim3(48, 8), blk, 0, stream>>>(Lb, Btp, inp, t2, 6144, 2.f, -1.f);
  vgen<<<8, blk, 0, stream>>>(u_gw, u_iw, u_ib, 6, 192, Vbu, bau);
  weightgen3<<<dim3(72, 16), blk, 0, stream>>>(emb, u_wpool, 64, 0, Wbuf);
  pernode3<<<1024, blk, 0, stream>>>(inp, t1, t2, Wbuf, emb, u_bpool, 64, 0, acc0);
  zgemm<<<dim3(2, 512), blk, 0, stream>>>(inpb, Vbu, bau, Z, 256);
  transpose_b2b<<<dim3(6, 32, 64), blk, 0, stream>>>(Z, 256, 192, Zt);
  mfma_k3<<<dim3(32, 8), blk, 0, stream>>>(chebb, Zt, u_gb, acc1, 4096, 6);
  att_reduce<64><<<dim3(16, 64), blk, 0, stream>>>(acc0, acc1, part0, part1);
  att_finish<64, 4><<<64, blk, 0, stream>>>(part0, part1, u_a1w1, u_a1w2, u_a2w1, u_a2w2, s12u);
  final_h<<<16384, blk, 0, stream>>>(acc0, acc1, s12u, rbuf, state, out);
}

// Round 8
// 840.042 us; speedup vs baseline: 3.9640x; 1.0284x over previous
//
#include <hip/hip_runtime.h>
#include <hip/hip_bf16.h>
#include <math.h>

// RGSLCell on MI355X. R8 = R7 + two fixes:
//  (1) BUG FIX: R6/R7 under-allocated Vbu (needs 12288 fl, had 9216) -> vgen's
//      zero-pad rows 192..255 clobbered bau (update cheb bias) with a race.
//  (2) precision margin: pernode/cand path back to fp32 (R5-proven 0.082):
//      mfma_stack writes fp32 t12; concat/gate_combine write fp32 + bf16;
//      pernode5 stages fp32 x. Keeps R6 structure (stacked [L;L2] one-GEMM,
//      compensated L2, stacked-K cheb) + R7's RNE rounding.
// Zbuf overlays dead t12 region -> ws ~240 MB (same as R7, which ran).

#define B_  64
#define N_  1024
#define CIN_ 96
#define R_  288

typedef __attribute__((ext_vector_type(8))) short bf16x8;
typedef __attribute__((ext_vector_type(4))) float f32x4;
typedef unsigned short u16;
typedef unsigned int u32;

__device__ __forceinline__ float lrelu(float v) { return v >= 0.f ? v : 0.01f * v; }
__device__ __forceinline__ float sigmoidf_(float u) { return 1.f / (1.f + expf(-u)); }
// round-to-nearest-even fp32 -> bf16
__device__ __forceinline__ u16 f2b(float f) {
  union { float f; u32 u; } c; c.f = f;
  u32 u = c.u;
  return (u16)((u + 0x7FFFu + ((u >> 16) & 1u)) >> 16);
}
__device__ __forceinline__ float b2f(u16 u) {
  union { u32 x; float f; } c; c.x = ((u32)u) << 16; return c.f;
}
__device__ __forceinline__ void gload_lds16(const u16* gp, u16* lp) {
  __builtin_amdgcn_global_load_lds((const __attribute__((address_space(1))) u32*)gp,
                                   (__attribute__((address_space(3))) u32*)lp, 16, 0, 0);
}

// ---------------------------------------------------------------------------
// concat: inp fp32 AND inpb bf16, layout [(n*64+b)][96]
__global__ __launch_bounds__(256) void concat_bf2(const float* __restrict__ x,
                                                  const float* __restrict__ st,
                                                  float* __restrict__ inp,
                                                  u16* __restrict__ inpb) {
  size_t t = (size_t)blockIdx.x * 256 + threadIdx.x;
  if (t >= (size_t)B_ * N_ * CIN_) return;
  int i = (int)(t % CIN_);
  size_t v = t / CIN_;
  size_t b = v & 63, n = v >> 6;
  float f = (i < 32) ? x[(b * N_ + n) * 32 + i] : st[(b * N_ + n) * 64 + (i - 32)];
  inp[t] = f;
  inpb[t] = f2b(f);
}

// fp32 -> bf16 flat convert (cheb)
__global__ __launch_bounds__(256) void conv_f2b(const float* __restrict__ in,
                                                u16* __restrict__ out, int n4) {
  int t = blockIdx.x * 256 + threadIdx.x;
  if (t >= n4) return;
  float4 v = ((const float4*)in)[t];
  ushort4 o;
  o.x = f2b(v.x); o.y = f2b(v.y); o.z = f2b(v.z); o.w = f2b(v.w);
  ((ushort4*)out)[t] = o;
}

// split fp32 -> (hi, lo) bf16 planes
__global__ __launch_bounds__(256) void split_hilo(const float* __restrict__ in,
                                                  u16* __restrict__ hi,
                                                  u16* __restrict__ lo, int n4) {
  int t = blockIdx.x * 256 + threadIdx.x;
  if (t >= n4) return;
  float4 v = ((const float4*)in)[t];
  ushort4 h, l;
  h.x = f2b(v.x); l.x = f2b(v.x - b2f(h.x));
  h.y = f2b(v.y); l.y = f2b(v.y - b2f(h.y));
  h.z = f2b(v.z); l.z = f2b(v.z - b2f(h.z));
  h.w = f2b(v.w); l.w = f2b(v.w - b2f(h.w));
  ((ushort4*)hi)[t] = h;
  ((ushort4*)lo)[t] = l;
}

// transpose fp32 [1024][1024] -> (hiT, loT) bf16 planes of L^T
__global__ __launch_bounds__(256) void transpose_split(const float* __restrict__ in,
                                                       u16* __restrict__ hiT,
                                                       u16* __restrict__ loT) {
  __shared__ float t[32][33];
  const int tid = threadIdx.x;
  const int j0 = blockIdx.x * 32, r0 = blockIdx.y * 32;
  const int tc = tid & 31, tr = tid >> 5;
#pragma unroll
  for (int q = 0; q < 4; ++q)
    t[tr + q * 8][tc] = in[(size_t)(r0 + tr + q * 8) * 1024 + j0 + tc];
  __syncthreads();
  const int jj = tid >> 3, rq = (tid & 7) * 4;
  ushort4 h, l;
#pragma unroll
  for (int q = 0; q < 4; ++q) {
    float v = t[rq + q][jj];
    u16 hh = f2b(v);
    ((u16*)&h)[q] = hh;
    ((u16*)&l)[q] = f2b(v - b2f(hh));
  }
  *(ushort4*)(hiT + (size_t)(j0 + jj) * N_ + r0 + rq) = h;
  *(ushort4*)(loT + (size_t)(j0 + jj) * N_ + r0 + rq) = l;
}

// transpose bf16 [(n*64+b)][Zs] -> bf16 [(b*Ctot+c)][1024]
__global__ __launch_bounds__(256) void transpose_b2b(const u16* __restrict__ Z, int Zs,
                                                     int Ctot, u16* __restrict__ Zt) {
  __shared__ u16 t[32][36];
  const int tid = threadIdx.x;
  const int c0 = blockIdx.x * 32, n0 = blockIdx.y * 32, b = blockIdx.z;
  {
    const int i = tid >> 3, c4 = (tid & 7) * 4;
    ushort4 v = *(const ushort4*)(Z + ((size_t)(n0 + i) * 64 + b) * Zs + c0 + c4);
    t[i][c4] = v.x; t[i][c4 + 1] = v.y; t[i][c4 + 2] = v.z; t[i][c4 + 3] = v.w;
  }
  __syncthreads();
  {
    const int c = tid >> 3, n4 = (tid & 7) * 4;
    ushort4 o;
    o.x = t[n4][c]; o.y = t[n4 + 1][c]; o.z = t[n4 + 2][c]; o.w = t[n4 + 3][c];
    *(ushort4*)(Zt + (size_t)(b * Ctot + c0 + c) * 1024 + n0 + n4) = o;
  }
}

// ---------------------------------------------------------------------------
// compensated L2: Y = bf16(2*(Lhi@Lhi + Llo@Lhi + Lhi@Llo) - I), 64x64 tiles
__global__ __launch_bounds__(256) void mfma_l2(const u16* __restrict__ Lhi,
                                               const u16* __restrict__ Llo,
                                               const u16* __restrict__ LhiT,
                                               const u16* __restrict__ LloT,
                                               u16* __restrict__ Y) {
  __shared__ u16 Asl[64 * 64];
  __shared__ u16 Bsl[64 * 64];
  const int tid = threadIdx.x;
  const int w = tid >> 6, lane = tid & 63;
  const int m0 = blockIdx.y * 64, n0 = blockIdx.x * 64;
  const int wr = w >> 1, wc = w & 1;
  const int sr = lane >> 3, so = lane & 7;
  const int cl = lane & 15, q4 = lane >> 4;
  f32x4 acc[2][2] = {};

  for (int ph = 0; ph < 3; ++ph) {
    const u16* A = (ph == 1) ? Llo : Lhi;
    const u16* B = (ph == 2) ? LloT : LhiT;
    for (int k0 = 0; k0 < 1024; k0 += 64) {
      __syncthreads();
#pragma unroll
      for (int i = 0; i < 2; ++i) {
        const int r = i * 32 + w * 8 + sr;
        const int o = so ^ (r & 7);
        gload_lds16(A + (size_t)(m0 + r) * 1024 + k0 + o * 8, Asl + (i * 32 + w * 8) * 64);
        gload_lds16(B + (size_t)(n0 + r) * 1024 + k0 + o * 8, Bsl + (i * 32 + w * 8) * 64);
      }
      __syncthreads();
#pragma unroll
      for (int kk = 0; kk < 2; ++kk) {
        bf16x8 af[2], bfr[2];
#pragma unroll
        for (int mi = 0; mi < 2; ++mi) {
          const int ra = wr * 32 + mi * 16 + cl;
          af[mi] = *(const bf16x8*)(Asl + ra * 64 + ((kk * 4 + q4) ^ (ra & 7)) * 8);
        }
#pragma unroll
        for (int ni = 0; ni < 2; ++ni) {
          const int rb = wc * 32 + ni * 16 + cl;
          bfr[ni] = *(const bf16x8*)(Bsl + rb * 64 + ((kk * 4 + q4) ^ (rb & 7)) * 8);
        }
#pragma unroll
        for (int mi = 0; mi < 2; ++mi)
#pragma unroll
          for (int ni = 0; ni < 2; ++ni)
            acc[mi][ni] = __builtin_amdgcn_mfma_f32_16x16x32_bf16(af[mi], bfr[ni], acc[mi][ni], 0, 0, 0);
      }
    }
  }
#pragma unroll
  for (int mi = 0; mi < 2; ++mi)
#pragma unroll
    for (int ni = 0; ni < 2; ++ni) {
      const int j = n0 + wc * 32 + ni * 16 + cl;
#pragma unroll
      for (int r = 0; r < 4; ++r) {
        const int m = m0 + wr * 32 + mi * 16 + q4 * 4 + r;
        float v = 2.f * acc[mi][ni][r] - (m == j ? 1.f : 0.f);
        Y[(size_t)m * 1024 + j] = f2b(v);
      }
    }
}

// ---------------------------------------------------------------------------
// MFMA GEMM, fp32 out: Y = A@B; A bf16 [M][1024], Bt bf16 [J][1024]. 128x128.
__global__ __launch_bounds__(256) void mfma_stack_f32(const u16* __restrict__ A,
                                                      const u16* __restrict__ Bt,
                                                      float* __restrict__ Y, int J) {
  __shared__ u16 Asl[128 * 64];
  __shared__ u16 Bsl[128 * 64];
  const int tid = threadIdx.x;
  const int w = tid >> 6, lane = tid & 63;
  const int m0 = blockIdx.y * 128, n0 = blockIdx.x * 128;
  const int wr = w >> 1, wc = w & 1;
  const int sr = lane >> 3, so = lane & 7;
  const int cl = lane & 15, q4 = lane >> 4;
  f32x4 acc[4][4] = {};

  for (int k0 = 0; k0 < 1024; k0 += 64) {
    __syncthreads();
#pragma unroll
    for (int i = 0; i < 4; ++i) {
      const int r = i * 32 + w * 8 + sr;
      const int o = so ^ (r & 7);
      gload_lds16(A + (size_t)(m0 + r) * 1024 + k0 + o * 8, Asl + (i * 32 + w * 8) * 64);
      gload_lds16(Bt + (size_t)(n0 + r) * 1024 + k0 + o * 8, Bsl + (i * 32 + w * 8) * 64);
    }
    __syncthreads();
#pragma unroll
    for (int kk = 0; kk < 2; ++kk) {
      bf16x8 af[4], bfr[4];
#pragma unroll
      for (int mi = 0; mi < 4; ++mi) {
        const int ra = wr * 64 + mi * 16 + cl;
        af[mi] = *(const bf16x8*)(Asl + ra * 64 + ((kk * 4 + q4) ^ (ra & 7)) * 8);
      }
#pragma unroll
      for (int ni = 0; ni < 4; ++ni) {
        const int rb = wc * 64 + ni * 16 + cl;
        bfr[ni] = *(const bf16x8*)(Bsl + rb * 64 + ((kk * 4 + q4) ^ (rb & 7)) * 8);
      }
#pragma unroll
      for (int mi = 0; mi < 4; ++mi)
#pragma unroll
        for (int ni = 0; ni < 4; ++ni)
          acc[mi][ni] = __builtin_amdgcn_mfma_f32_16x16x32_bf16(af[mi], bfr[ni], acc[mi][ni], 0, 0, 0);
    }
  }
#pragma unroll
  for (int mi = 0; mi < 4; ++mi)
#pragma unroll
    for (int ni = 0; ni < 4; ++ni) {
      const int j = n0 + wc * 64 + ni * 16 + cl;
#pragma unroll
      for (int r = 0; r < 4; ++r) {
        const int m = m0 + wr * 64 + mi * 16 + q4 * 4 + r;
        Y[(size_t)m * J + j] = acc[mi][ni][r];
      }
    }
}

// ---------------------------------------------------------------------------
// vgen: V[c][i] = sum_j gw[o][k*O+j]*iw[j][i]; ball[c] = gw-row @ ib
// NOTE: writes ALL grid rows (zero-pad for c >= Ctot) -> Vb must be allocated
// for gridDim.x*32 rows (R6/R7 bug: under-allocated -> clobbered ball).
__global__ __launch_bounds__(256) void vgen(const float* __restrict__ gw,
                                            const float* __restrict__ iw,
                                            const float* __restrict__ ib,
                                            int oshift, int Ctot,
                                            u16* __restrict__ Vb,
                                            float* __restrict__ ball) {
  __shared__ float siw[128 * 96];
  __shared__ float sib[128];
  const int O = 1 << oshift;
  const int c0 = blockIdx.x * 32;
  for (int e = threadIdx.x; e < O * 96; e += 256) siw[e] = iw[e];
  for (int e = threadIdx.x; e < O; e += 256) sib[e] = ib[e];
  __syncthreads();
  for (int idx = threadIdx.x; idx < 32 * 97; idx += 256) {
    int cl = idx / 97, col = idx - cl * 97;
    int c = c0 + cl;
    float s = 0.f;
    if (c < Ctot) {
      int o = c & (O - 1), k = c >> oshift;
      const float* g = gw + (size_t)o * (3 * O) + k * O;
      if (col < 96) { for (int j = 0; j < O; ++j) s += g[j] * siw[j * 96 + col]; }
      else          { for (int j = 0; j < O; ++j) s += g[j] * sib[j]; }
    }
    if (col < 96) Vb[(size_t)c * 96 + col] = f2b(s);
    else ball[c] = s;
  }
}

// ---------------------------------------------------------------------------
// zgemm: Z[M][Zs] bf16 = A[M][96] @ Vb^T + ball. 128x128 tile, BK=32 x 3.
__global__ __launch_bounds__(256) void zgemm(const u16* __restrict__ A,
                                             const u16* __restrict__ Bt,
                                             const float* __restrict__ ball,
                                             u16* __restrict__ Z, int Zs) {
  __shared__ u16 Asl[128 * 32];
  __shared__ u16 Bsl[128 * 32];
  const int tid = threadIdx.x;
  const int w = tid >> 6, lane = tid & 63;
  const int m0 = blockIdx.y * 128, n0 = blockIdx.x * 128;
  const int wr = w >> 1, wc = w & 1;
  const int sr = lane >> 2, so = lane & 3;
  const int cl = lane & 15, q4 = lane >> 4;
  f32x4 acc[4][4] = {};
  for (int k0 = 0; k0 < 96; k0 += 32) {
    __syncthreads();
#pragma unroll
    for (int i = 0; i < 2; ++i) {
      const int r = i * 64 + w * 16 + sr;
      const int o = so ^ (r & 3);
      gload_lds16(A + (size_t)(m0 + r) * 96 + k0 + o * 8, Asl + (i * 64 + w * 16) * 32);
      gload_lds16(Bt + (size_t)(n0 + r) * 96 + k0 + o * 8, Bsl + (i * 64 + w * 16) * 32);
    }
    __syncthreads();
    bf16x8 af[4], bfr[4];
#pragma unroll
    for (int mi = 0; mi < 4; ++mi) {
      const int ra = wr * 64 + mi * 16 + cl;
      af[mi] = *(const bf16x8*)(Asl + ra * 32 + (q4 ^ (ra & 3)) * 8);
    }
#pragma unroll
    for (int ni = 0; ni < 4; ++ni) {
      const int rb = wc * 64 + ni * 16 + cl;
      bfr[ni] = *(const bf16x8*)(Bsl + rb * 32 + (q4 ^ (rb & 3)) * 8);
    }
#pragma unroll
    for (int mi = 0; mi < 4; ++mi)
#pragma unroll
      for (int ni = 0; ni < 4; ++ni)
        acc[mi][ni] = __builtin_amdgcn_mfma_f32_16x16x32_bf16(af[mi], bfr[ni], acc[mi][ni], 0, 0, 0);
  }
#pragma unroll
  for (int mi = 0; mi < 4; ++mi)
#pragma unroll
    for (int ni = 0; ni < 4; ++ni) {
      const int c = n0 + wc * 64 + ni * 16 + cl;
      const float bb = ball[c];
#pragma unroll
      for (int r = 0; r < 4; ++r) {
        const int m = m0 + wr * 64 + mi * 16 + q4 * 4 + r;
        Z[(size_t)m * Zs + c] = f2b(acc[mi][ni][r] + bb);
      }
    }
}

// ---------------------------------------------------------------------------
// stacked-K cheb GEMM: Y[1024][J] = sum_kb cheb_kb @ Zt-slice + gb[j & omask]
__global__ __launch_bounds__(256) void mfma_k3(const u16* __restrict__ A3,
                                               const u16* __restrict__ Zt,
                                               const float* __restrict__ gb,
                                               float* __restrict__ Y,
                                               int J, int obits) {
  __shared__ u16 Asl[128 * 64];
  __shared__ u16 Bsl[128 * 64];
  const int tid = threadIdx.x;
  const int w = tid >> 6, lane = tid & 63;
  const int m0 = blockIdx.y * 128, n0 = blockIdx.x * 128;
  const int wr = w >> 1, wc = w & 1;
  const int sr = lane >> 3, so = lane & 7;
  const int cl = lane & 15, q4 = lane >> 4;
  const int omask = (1 << obits) - 1;
  f32x4 acc[4][4] = {};

  for (int k0 = 0; k0 < 3072; k0 += 64) {
    const int kb = k0 >> 10, ko = k0 & 1023;
    __syncthreads();
#pragma unroll
    for (int i = 0; i < 4; ++i) {
      const int r = i * 32 + w * 8 + sr;
      const int o = so ^ (r & 7);
      gload_lds16(A3 + (size_t)kb * 1048576 + (size_t)(m0 + r) * 1024 + ko + o * 8,
                  Asl + (i * 32 + w * 8) * 64);
      const int jp = n0 + r;
      const int brow = (((jp >> obits) * 3 + kb) << obits) | (jp & omask);
      gload_lds16(Zt + (size_t)brow * 1024 + ko + o * 8, Bsl + (i * 32 + w * 8) * 64);
    }
    __syncthreads();
#pragma unroll
    for (int kk = 0; kk < 2; ++kk) {
      bf16x8 af[4], bfr[4];
#pragma unroll
      for (int mi = 0; mi < 4; ++mi) {
        const int ra = wr * 64 + mi * 16 + cl;
        af[mi] = *(const bf16x8*)(Asl + ra * 64 + ((kk * 4 + q4) ^ (ra & 7)) * 8);
      }
#pragma unroll
      for (int ni = 0; ni < 4; ++ni) {
        const int rb = wc * 64 + ni * 16 + cl;
        bfr[ni] = *(const bf16x8*)(Bsl + rb * 64 + ((kk * 4 + q4) ^ (rb & 7)) * 8);
      }
#pragma unroll
      for (int mi = 0; mi < 4; ++mi)
#pragma unroll
        for (int ni = 0; ni < 4; ++ni)
          acc[mi][ni] = __builtin_amdgcn_mfma_f32_16x16x32_bf16(af[mi], bfr[ni], acc[mi][ni], 0, 0, 0);
    }
  }
#pragma unroll
  for (int mi = 0; mi < 4; ++mi)
#pragma unroll
    for (int ni = 0; ni < 4; ++ni) {
      const int j = n0 + wc * 64 + ni * 16 + cl;
      const float bb = gb[j & omask];
#pragma unroll
      for (int r = 0; r < 4; ++r) {
        const int m = m0 + wr * 64 + mi * 16 + q4 * 4 + r;
        Y[(size_t)m * J + j] = acc[mi][ni][r] + bb;
      }
    }
}

// ---------------------------------------------------------------------------
// weightgen: W[n][r=288][64] bf16 = sum_d emb[n][d] * wpool[d][r][o0+o]
__global__ __launch_bounds__(256) void weightgen3(const float* __restrict__ emb,
                                                  const float* __restrict__ wpool,
                                                  int Otot, int o0, u16* __restrict__ W) {
  const int tid = threadIdx.x;
  const int ro = blockIdx.x * 256 + tid;
  const int r = ro >> 6, o = ro & 63;
  const int n0 = blockIdx.y * 64;
  __shared__ float semb[64][17];
  for (int e = tid; e < 1024; e += 256) semb[e >> 4][e & 15] = emb[(n0 + (e >> 4)) * 16 + (e & 15)];
  __syncthreads();
  float wv[16];
#pragma unroll
  for (int d = 0; d < 16; ++d) wv[d] = wpool[((size_t)d * R_ + r) * Otot + o0 + o];
#pragma unroll 4
  for (int n = 0; n < 64; ++n) {
    float s = 0.f;
#pragma unroll
    for (int d = 0; d < 16; ++d) s += semb[n][d] * wv[d];
    W[(size_t)(n0 + n) * (R_ * 64) + ro] = f2b(s);
  }
}

// pernode5: fp32 x inputs (R5-proven precision). xa fp32 [(n*64+b)][96];
// xbc fp32 t12 [2048][6144] (row n -> t1, row 1024+n -> t2). W bf16.
__global__ __launch_bounds__(256) void pernode5(const float* __restrict__ xa,
                                                const float* __restrict__ xbc,
                                                const u16* __restrict__ W,
                                                const float* __restrict__ emb,
                                                const float* __restrict__ bpool,
                                                int Otot, int o0,
                                                float* __restrict__ outp) {
  const int n = blockIdx.x;
  const int tid = threadIdx.x;
  __shared__ float sW[32][68];
  __shared__ float sX[32][68];
  __shared__ float semb[16];
  if (tid < 16) semb[tid] = emb[n * 16 + tid];
  const int tx = tid & 31, tb = tid >> 5;
  const int lb = tid >> 2, li = (tid & 3) * 8;
  float acc[8][2] = {};
  const u16* Wn = W + (size_t)n * (R_ * 64);

  for (int c = 0; c < 9; ++c) {
    const int k = c / 3, i0 = (c % 3) * 32;
    const float* xk = (k == 0) ? (xa + (size_t)n * 6144)
                               : (xbc + ((size_t)(k - 1) * 1024 + n) * 6144);
    __syncthreads();
    {  // stage W chunk bf16 -> fp32 LDS
      const int row = tid >> 3, o8 = (tid & 7) * 8;
      uint4 v = *(const uint4*)(Wn + (size_t)(c * 32 + row) * 64 + o8);
      sW[row][o8 + 0] = b2f((u16)(v.x & 0xFFFF)); sW[row][o8 + 1] = b2f((u16)(v.x >> 16));
      sW[row][o8 + 2] = b2f((u16)(v.y & 0xFFFF)); sW[row][o8 + 3] = b2f((u16)(v.y >> 16));
      sW[row][o8 + 4] = b2f((u16)(v.z & 0xFFFF)); sW[row][o8 + 5] = b2f((u16)(v.z >> 16));
      sW[row][o8 + 6] = b2f((u16)(v.w & 0xFFFF)); sW[row][o8 + 7] = b2f((u16)(v.w >> 16));
    }
    {  // stage fp32 x slice
      const float* p = xk + (size_t)lb * 96 + i0 + li;
      float4 v0 = *(const float4*)p;
      float4 v1 = *(const float4*)(p + 4);
      sX[li + 0][lb] = v0.x; sX[li + 1][lb] = v0.y;
      sX[li + 2][lb] = v0.z; sX[li + 3][lb] = v0.w;
      sX[li + 4][lb] = v1.x; sX[li + 5][lb] = v1.y;
      sX[li + 6][lb] = v1.z; sX[li + 7][lb] = v1.w;
    }
    __syncthreads();
#pragma unroll
    for (int il = 0; il < 32; ++il) {
      float xv[8], wv[2];
#pragma unroll
      for (int j = 0; j < 8; ++j) xv[j] = sX[il][tb * 8 + j];
      wv[0] = sW[il][tx * 2]; wv[1] = sW[il][tx * 2 + 1];
#pragma unroll
      for (int j = 0; j < 8; ++j) { acc[j][0] += xv[j] * wv[0]; acc[j][1] += xv[j] * wv[1]; }
    }
  }
  float bias[2];
#pragma unroll
  for (int qq = 0; qq < 2; ++qq) {
    int o = o0 + tx * 2 + qq;
    float s = 0.f;
#pragma unroll
    for (int d = 0; d < 16; ++d) s += semb[d] * bpool[d * Otot + o];
    bias[qq] = s;
  }
#pragma unroll
  for (int j = 0; j < 8; ++j) {
    size_t base = ((size_t)n * B_ + tb * 8 + j) * Otot + o0 + tx * 2;
    outp[base] = acc[j][0] + bias[0];
    outp[base + 1] = acc[j][1] + bias[1];
  }
}

// ---------------------------------------------------------------------------
// two-stage attention mean
template <int C>
__global__ __launch_bounds__(256) void att_reduce(const float* __restrict__ A0,
                                                  const float* __restrict__ A1,
                                                  float* __restrict__ part0,
                                                  float* __restrict__ part1) {
  constexpr int C4 = C / 4;
  constexpr int H = 256 / C4;
  const int chunk = blockIdx.x;
  const int b = blockIdx.y;
  const int tid = threadIdx.x;
  const int c4 = tid % C4, h = tid / C4;
  __shared__ float4 r0[256], r1[256];
  float4 s0 = {0.f, 0.f, 0.f, 0.f}, s1 = {0.f, 0.f, 0.f, 0.f};
  const float4* p0 = (const float4*)(A0 + (size_t)b * C) + c4;
  const float4* p1 = (const float4*)(A1 + (size_t)b * C) + c4;
  const size_t stride = (size_t)B_ * C4;
  for (int n = chunk * 64 + h; n < chunk * 64 + 64; n += H) {
    float4 v0 = p0[(size_t)n * stride];
    float4 v1 = p1[(size_t)n * stride];
    s0.x += lrelu(v0.x); s0.y += lrelu(v0.y); s0.z += lrelu(v0.z); s0.w += lrelu(v0.w);
    s1.x += lrelu(v1.x); s1.y += lrelu(v1.y); s1.z += lrelu(v1.z); s1.w += lrelu(v1.w);
  }
  r0[tid] = s0; r1[tid] = s1;
  __syncthreads();
  if (h == 0) {
    for (int hh = 1; hh < H; ++hh) {
      float4 a = r0[c4 + hh * C4], bb = r1[c4 + hh * C4];
      s0.x += a.x; s0.y += a.y; s0.z += a.z; s0.w += a.w;
      s1.x += bb.x; s1.y += bb.y; s1.z += bb.z; s1.w += bb.w;
    }
    ((float4*)(part0 + ((size_t)b * 16 + chunk) * C))[c4] = s0;
    ((float4*)(part1 + ((size_t)b * 16 + chunk) * C))[c4] = s1;
  }
}

template <int C, int HID>
__global__ __launch_bounds__(256) void att_finish(const float* __restrict__ part0,
                                                  const float* __restrict__ part1,
                                                  const float* __restrict__ w11,
                                                  const float* __restrict__ w12,
                                                  const float* __restrict__ w21,
                                                  const float* __restrict__ w22,
                                                  float* __restrict__ sout) {
  const int b = blockIdx.x;
  const int tid = threadIdx.x;
  __shared__ float sm0[C], sm1[C];
  __shared__ float h0[HID], h1[HID];
  if (tid < C) {
    float s0 = 0.f, s1 = 0.f;
    for (int ch = 0; ch < 16; ++ch) {
      s0 += part0[((size_t)b * 16 + ch) * C + tid];
      s1 += part1[((size_t)b * 16 + ch) * C + tid];
    }
    sm0[tid] = s0 * (1.f / N_); sm1[tid] = s1 * (1.f / N_);
  }
  __syncthreads();
  if (tid < HID) {
    float a = 0.f;
    for (int cc = 0; cc < C; ++cc) a += sm0[cc] * w11[tid * C + cc];
    h0[tid] = fmaxf(a, 0.f);
  } else if (tid >= 32 && tid < 32 + HID) {
    int j = tid - 32;
    float a = 0.f;
    for (int cc = 0; cc < C; ++cc) a += sm1[cc] * w21[j * C + cc];
    h1[j] = fmaxf(a, 0.f);
  }
  __syncthreads();
  if (tid == 0) {
    float a = 0.f;
    for (int j = 0; j < HID; ++j) a += h0[j] * w12[j];
    sout[b] = sigmoidf_(a);
  } else if (tid == 32) {
    float a = 0.f;
    for (int j = 0; j < HID; ++j) a += h1[j] * w22[j];
    sout[B_ + b] = sigmoidf_(a);
  }
}

// ---------------------------------------------------------------------------
// gate combine -> cand fp32 + candb bf16 + rbuf fp32
__global__ __launch_bounds__(256) void gate_combine_b2(const float* __restrict__ a0,
                                                       const float* __restrict__ a1,
                                                       const float* __restrict__ s12,
                                                       const float* __restrict__ x,
                                                       const float* __restrict__ st,
                                                       float* __restrict__ cand,
                                                       u16* __restrict__ candb,
                                                       float* __restrict__ rbuf) {
  size_t t = (size_t)blockIdx.x * 256 + threadIdx.x;
  if (t >= (size_t)B_ * N_ * 64) return;
  int c = (int)(t & 63);
  int b = (int)((t >> 6) & 63);
  int n = (int)(t >> 12);
  float s1 = s12[b], s2 = s12[B_ + b];
  size_t nb = (size_t)n * B_ + b;
  size_t i128 = nb * 128;
  float uz = s1 * lrelu(a0[i128 + c]) + s2 * lrelu(a1[i128 + c]);
  float ur = s1 * lrelu(a0[i128 + 64 + c]) + s2 * lrelu(a1[i128 + 64 + c]);
  float z = sigmoidf_(uz);
  float r = sigmoidf_(ur);
  float stv = st[((size_t)b * N_ + n) * 64 + c];
  float zs = z * stv;
  cand[nb * CIN_ + 32 + c] = zs;
  candb[nb * CIN_ + 32 + c] = f2b(zs);
  rbuf[nb * 64 + c] = r;
  if (c < 32) {
    float xv = x[((size_t)b * N_ + n) * 32 + c];
    cand[nb * CIN_ + c] = xv;
    candb[nb * CIN_ + c] = f2b(xv);
  }
}

__global__ __launch_bounds__(256) void final_h(const float* __restrict__ a0,
                                               const float* __restrict__ a1,
                                               const float* __restrict__ s12,
                                               const float* __restrict__ rbuf,
                                               const float* __restrict__ st,
                                               float* __restrict__ out) {
  size_t t = (size_t)blockIdx.x * 256 + threadIdx.x;
  if (t >= (size_t)B_ * N_ * 64) return;
  int o = (int)(t & 63);
  int n = (int)((t >> 6) & 1023);
  int b = (int)(t >> 16);
  float s1 = s12[b], s2 = s12[B_ + b];
  size_t nb = ((size_t)n * B_ + b) * 64 + o;
  float u = s1 * lrelu(a0[nb]) + s2 * lrelu(a1[nb]);
  float hc = tanhf(u);
  float r = rbuf[nb];
  out[t] = r * st[t] + (1.f - r) * hc;
}

// ---------------------------------------------------------------------------
extern "C" void kernel_launch(void* const* d_in, const int* in_sizes, int n_in,
                              void* d_out, int out_size, void* d_ws, size_t ws_size,
                              hipStream_t stream) {
  const float* x       = (const float*)d_in[0];
  const float* state   = (const float*)d_in[1];
  const float* emb     = (const float*)d_in[2];
  const float* Ltil    = (const float*)d_in[3];
  const float* cheb    = (const float*)d_in[4];
  const float* g_wpool = (const float*)d_in[5];
  const float* g_bpool = (const float*)d_in[6];
  const float* g_iw    = (const float*)d_in[7];
  const float* g_ib    = (const float*)d_in[8];
  const float* g_gw    = (const float*)d_in[9];
  const float* g_gb    = (const float*)d_in[10];
  const float* g_a1w1  = (const float*)d_in[11];
  const float* g_a1w2  = (const float*)d_in[12];
  const float* g_a2w1  = (const float*)d_in[13];
  const float* g_a2w2  = (const float*)d_in[14];
  const float* u_wpool = (const float*)d_in[15];
  const float* u_bpool = (const float*)d_in[16];
  const float* u_iw    = (const float*)d_in[17];
  const float* u_ib    = (const float*)d_in[18];
  const float* u_gw    = (const float*)d_in[19];
  const float* u_gb    = (const float*)d_in[20];
  const float* u_a1w1  = (const float*)d_in[21];
  const float* u_a1w2  = (const float*)d_in[22];
  const float* u_a2w1  = (const float*)d_in[23];
  const float* u_a2w2  = (const float*)d_in[24];
  float* out = (float*)d_out;

  // workspace (float offsets), ~240.3 MB (R7 ran at ~240.2 MB)
  float* ws    = (float*)d_ws;
  float* inp   = ws;                       // [65536][96] fp32 (later cand)
  u16*   inpb  = (u16*)(ws + 6291456);     // [65536][96] bf16 (later candb)
  float* t12   = ws + 9437184;             // [2048][6144] fp32; Zbuf overlays
  u16*   Zbuf  = (u16*)t12;                //   gate [65536][384] bf16 (exact fit)
  u16*   Wbuf  = (u16*)(ws + 22020096);    // [1024][288][64] bf16
  u16*   Btp   = (u16*)(ws + 31457280);    // [6144][1024] bf16
  u16*   Zt    = Wbuf;                     // overlay Wbuf+Btp: [24576][1024]
  float* acc1  = ws + 34603008;            // [n,b,128]
  float* acc0  = ws + 42991616;            // [n,b,128]
  u16*   LbStk = (u16*)(ws + 51380224);    // [2048][1024] bf16 (Lhi ; L2)
  u16*   chebb = (u16*)(ws + 52428800);    // [3][1024][1024] bf16
  float* s12   = ws + 54001664;
  float* s12u  = ws + 54001792;
  float* part0 = ws + 54001920;            // [64][16][128]
  float* part1 = ws + 54132992;
  float* rbuf  = ws + 54264064;            // [n,b,64]
  u16*   Vbg   = (u16*)(ws + 58458368);    // [384][96] = 18432 fl
  float* bag   = ws + 58476800;            // [384]
  u16*   Vbu   = (u16*)(ws + 58477184);    // [256][96] = 12288 fl (FULL alloc)
  float* bau   = ws + 58489472;            // [256]
  u16*   LhiT  = (u16*)(ws + 58489728);    // [1024][1024] bf16
  u16*   LloT  = (u16*)(ws + 59014016);    // [1024][1024] bf16
  u16*   Llo   = (u16*)(ws + 59538304);    // [1024][1024] bf16  (end 60,062,592)

  dim3 blk(256);

  // ---- init: Lhi/Llo planes, compensated L2 = 2L@L - I, chebb ----
  split_hilo<<<1024, blk, 0, stream>>>(Ltil, LbStk, Llo, 262144);
  transpose_split<<<dim3(32, 32), blk, 0, stream>>>(Ltil, LhiT, LloT);
  mfma_l2<<<dim3(16, 16), blk, 0, stream>>>(LbStk, Llo, LhiT, LloT, LbStk + 1048576);
  conv_f2b<<<3072, blk, 0, stream>>>(cheb, chebb, 786432);

  // ---- gate AVWGCN (dim_out = 128) ----
  concat_bf2<<<24576, blk, 0, stream>>>(x, state, inp, inpb);
  transpose_b2b<<<dim3(3, 32, 64), blk, 0, stream>>>(inpb, 96, 96, Btp);
  mfma_stack_f32<<<dim3(48, 16), blk, 0, stream>>>(LbStk, Btp, t12, 6144);
  vgen<<<12, blk, 0, stream>>>(g_gw, g_iw, g_ib, 7, 384, Vbg, bag);
  for (int half = 0; half < 2; ++half) {
    weightgen3<<<dim3(72, 16), blk, 0, stream>>>(emb, g_wpool, 128, half * 64, Wbuf);
    pernode5<<<1024, blk, 0, stream>>>(inp, t12, Wbuf, emb, g_bpool, 128, half * 64, acc0);
  }
  zgemm<<<dim3(3, 512), blk, 0, stream>>>(inpb, Vbg, bag, Zbuf, 384);   // overlays t12 (dead)
  transpose_b2b<<<dim3(12, 32, 64), blk, 0, stream>>>(Zbuf, 384, 384, Zt);  // kills Wbuf/Btp
  mfma_k3<<<dim3(64, 8), blk, 0, stream>>>(chebb, Zt, g_gb, acc1, 8192, 7);
  att_reduce<128><<<dim3(16, 64), blk, 0, stream>>>(acc0, acc1, part0, part1);
  att_finish<128, 8><<<64, blk, 0, stream>>>(part0, part1, g_a1w1, g_a1w2, g_a2w1, g_a2w2, s12);
  gate_combine_b2<<<16384, blk, 0, stream>>>(acc0, acc1, s12, x, state, inp, inpb, rbuf);

  // ---- update AVWGCN (dim_out = 64), input = cand/candb ----
  transpose_b2b<<<dim3(3, 32, 64), blk, 0, stream>>>(inpb, 96, 96, Btp);
  mfma_stack_f32<<<dim3(48, 16), blk, 0, stream>>>(LbStk, Btp, t12, 6144);
  vgen<<<8, blk, 0, stream>>>(u_gw, u_iw, u_ib, 6, 192, Vbu, bau);
  weightgen3<<<dim3(72, 16), blk, 0, stream>>>(emb, u_wpool, 64, 0, Wbuf);
  pernode5<<<1024, blk, 0, stream>>>(inp, t12, Wbuf, emb, u_bpool, 64, 0, acc0);
  zgemm<<<dim3(2, 512), blk, 0, stream>>>(inpb, Vbu, bau, Zbuf, 256);
  transpose_b2b<<<dim3(6, 32, 64), blk, 0, stream>>>(Zbuf, 256, 192, Zt);
  mfma_k3<<<dim3(32, 8), blk, 0, stream>>>(chebb, Zt, u_gb, acc1, 4096, 6);
  att_reduce<64><<<dim3(16, 64), blk, 0, stream>>>(acc0, acc1, part0, part1);
  att_finish<64, 4><<<64, blk, 0, stream>>>(part0, part1, u_a1w1, u_a1w2, u_a2w1, u_a2w2, s12u);
  final_h<<<16384, blk, 0, stream>>>(acc0, acc1, s12u, rbuf, state, out);
}